// Round 20
// baseline (139.144 us; speedup 1.0000x reference)
//
#include <hip/hip_runtime.h>
#include <math.h>
#include <stdint.h>

#define B_   4
#define C_   256
#define H_   64
#define W_   64
#define CC_  64
#define OE_  196
#define OH_  128
#define OW_  128
#define XP_  70    // padded spatial dim for xtp (64 + 2*3)

typedef uint32_t u32;
typedef unsigned short u16;
typedef __attribute__((ext_vector_type(8))) short bf16x8;
typedef __attribute__((ext_vector_type(4))) float f32x4;
typedef __attribute__((ext_vector_type(4))) u32 u32x4;
typedef __attribute__((ext_vector_type(2))) u32 u32x2;

__device__ __forceinline__ u16 f2bf(float f) {
  u32 u = __builtin_bit_cast(u32, f);
  u32 r = (u + 0x7FFFu + ((u >> 16) & 1u)) >> 16;   // RNE
  return (u16)r;
}

// ------------------------------------------------------------------
// Kernel 0: weight re-layouts + xtp zeroing.
// ------------------------------------------------------------------
__global__ __launch_bounds__(256) void prep_weights(
    const float* __restrict__ w_comp, const float* __restrict__ w_enc,
    float* __restrict__ wct, u16* __restrict__ wfrag,
    float* __restrict__ xtp) {
  int idx = blockIdx.x * 256 + threadIdx.x;    // 0..65535
  if (idx < 50 * 14 * 64) {
    int lane = idx & 63;
    int mt   = (idx >> 6) % 14;
    int ks   = idx / (14 * 64);
    int o    = mt * 16 + (lane & 15);
    int tap  = ks >> 1, s = ks & 1;
    int ky   = tap / 5, kx = tap % 5;
    int cb   = s * 32 + (lane >> 4) * 8;
    u32 pk[4];
    #pragma unroll
    for (int p = 0; p < 4; ++p) {
      u16 lo = 0, hi = 0;
      if (o < OE_) {
        lo = f2bf(w_enc[((o * CC_ + cb + 2 * p) * 5 + ky) * 5 + kx]);
        hi = f2bf(w_enc[((o * CC_ + cb + 2 * p + 1) * 5 + ky) * 5 + kx]);
      }
      pk[p] = (u32)lo | ((u32)hi << 16);
    }
    *reinterpret_cast<u32x4*>(wfrag + (size_t)idx * 8) =
        *reinterpret_cast<u32x4*>(pk);
  }
  if (idx < C_ * CC_) {
    int cc = idx / C_, c = idx % C_;
    wct[c * CC_ + cc] = w_comp[cc * C_ + c];
  }
  // zero all of xtp (1,254,400 f32x4 chunks)
  {
    f32x4 z = {0.f, 0.f, 0.f, 0.f};
    for (int i = idx; i < B_ * XP_ * XP_ * C_ / 4; i += 65536)
      *reinterpret_cast<f32x4*>(xtp + (size_t)i * 4) = z;
  }
}

// ------------------------------------------------------------------
// Kernel 1: 1x1 compressor — comp bf16 + PADDED fp32 xtp.
// ------------------------------------------------------------------
__global__ __launch_bounds__(256) void compress_k(
    const float* __restrict__ x, const float* __restrict__ wct,
    const float* __restrict__ b_comp, u16* __restrict__ comp,
    float* __restrict__ xtp) {
  __shared__ float xs[C_ * 20];
  int t   = threadIdx.x;
  int gid = blockIdx.x;
  int wq  = gid & 3;
  int bh  = gid >> 2;
  int b = bh >> 6, h = bh & 63;
  int w0 = wq * 16;

  const float* xrow = x + (size_t)b * C_ * H_ * W_ + (size_t)h * W_ + w0;
  for (int i = t; i < 1024; i += 256) {
    int c = i >> 2, q = i & 3;
    f32x4 v = *reinterpret_cast<const f32x4*>(xrow + (size_t)c * H_ * W_ + q * 4);
    *reinterpret_cast<f32x4*>(xs + c * 20 + q * 4) = v;
  }
  __syncthreads();

  int w = t & 15, cq = t >> 4;   // cq 0..15 -> 4 cc each
  float acc[4] = {0.f, 0.f, 0.f, 0.f};
  for (int c = 0; c < C_; ++c) {
    float xv = xs[c * 20 + w];
    const float* wr = wct + c * CC_ + cq * 4;
    #pragma unroll
    for (int i = 0; i < 4; ++i) acc[i] = fmaf(xv, wr[i], acc[i]);
  }
  u32 pk[2];
  #pragma unroll
  for (int p = 0; p < 2; ++p) {
    u16 lo = f2bf(acc[2 * p]     + b_comp[cq * 4 + 2 * p]);
    u16 hi = f2bf(acc[2 * p + 1] + b_comp[cq * 4 + 2 * p + 1]);
    pk[p] = (u32)lo | ((u32)hi << 16);
  }
  *reinterpret_cast<u32x2*>(comp + ((size_t)bh * 64 + w0 + w) * CC_ + cq * 4) =
      *reinterpret_cast<u32x2*>(pk);

  // ---- xtp (padded f32): thread (w,cq) packs channels cq*16..+15 ----
  {
    float* dst = xtp + (((size_t)(b * XP_ + h + 3)) * XP_ + w0 + w + 3) * C_ + cq * 16;
    #pragma unroll
    for (int i = 0; i < 4; ++i) {
      int c = cq * 16 + i * 4;
      f32x4 v = {xs[c * 20 + w], xs[(c + 1) * 20 + w],
                 xs[(c + 2) * 20 + w], xs[(c + 3) * 20 + w]};
      *reinterpret_cast<f32x4*>(dst + i * 4) = v;
    }
  }
}

// ------------------------------------------------------------------
// Kernel 2: encoder MFMA GEMM v9 — fully-unrolled K-loop, 4-buffer
// rotation (unchanged from R18).
// ------------------------------------------------------------------
#define ELG_ 32256   // 224*36*4

__device__ __forceinline__ void enc_lda(
    bf16x8 (&a)[2], const u16* __restrict__ wfrag,
    int ks, int mtbase, int lane) {
  #pragma unroll
  for (int mm = 0; mm < 2; ++mm)
    a[mm] = *reinterpret_cast<const bf16x8*>(
        wfrag + (((size_t)ks * 14 + mtbase + mm) * 64 + lane) * 8);
}

__device__ __forceinline__ void enc_step(
    int ks, const char* lds, const bf16x8 (&a)[2], f32x4 (&acc)[2][2],
    int nlane, int kq) {
  int tap = ks >> 1, s = ks & 1;
  int ky = tap / 5, kx = tap % 5;   // constants after full unroll
  bf16x8 bf[2];
  #pragma unroll
  for (int nt = 0; nt < 2; ++nt) {
    int col = nt * 16 + nlane + kx;
    int byte = (((ky * 36 + col) * 64 + s * 32 + kq * 8) * 2) ^ ((col & 7) << 4);
    bf[nt] = *reinterpret_cast<const bf16x8*>(lds + byte);
  }
  #pragma unroll
  for (int mm = 0; mm < 2; ++mm)
    #pragma unroll
    for (int nt = 0; nt < 2; ++nt)
      acc[mm][nt] = __builtin_amdgcn_mfma_f32_16x16x32_bf16(
          a[mm], bf[nt], acc[mm][nt], 0, 0, 0);
}

__global__ __launch_bounds__(512) void enc_mfma_k(
    const u16* __restrict__ comp, const u16* __restrict__ wfrag,
    const float* __restrict__ b_enc, u16* __restrict__ smax) {
  __shared__ __align__(16) char lds[ELG_];

  int t   = threadIdx.x;                   // 0..511
  int bid = blockIdx.x;
  int swz = (bid & 7) * 64 + (bid >> 3);   // 512 blocks, bijective
  int wh  = swz & 1;
  int bh  = swz >> 1;
  int b = bh >> 6, h = bh & 63;
  int w0 = wh * 32;

  {
    const u16* cbse = comp + (size_t)b * H_ * W_ * CC_;
    for (int i = t; i < 1440; i += 512) {
      int q = i & 7, colr = i >> 3;
      int col = colr % 36, r = colr / 36;
      int hh = h - 2 + r, gw = w0 - 2 + col;
      u32x4 v = {0, 0, 0, 0};
      if ((unsigned)hh < H_ && (unsigned)gw < W_)
        v = *reinterpret_cast<const u32x4*>(cbse + ((size_t)hh * W_ + gw) * CC_ + q * 8);
      int byte = ((r * 36 + col) * 128 + q * 16) ^ ((col & 7) << 4);
      *reinterpret_cast<u32x4*>(lds + byte) = v;
    }
  }
  __syncthreads();   // B ready; no further barriers in K-loop

  int wv    = __builtin_amdgcn_readfirstlane(t >> 6);   // 0..7
  int lane  = t & 63;
  int nlane = lane & 15, kq = lane >> 4;
  int mtbase = wv * 2;

  f32x4 acc[2][2];
  #pragma unroll
  for (int mm = 0; mm < 2; ++mm)
    #pragma unroll
    for (int nt = 0; nt < 2; ++nt) acc[mm][nt] = (f32x4){0.f, 0.f, 0.f, 0.f};

  if (wv < 7) {
    bf16x8 abuf[4][2];
    #pragma unroll
    for (int p = 0; p < 4; ++p) enc_lda(abuf[p], wfrag, p, mtbase, lane);
    #pragma unroll
    for (int ks = 0; ks < 50; ++ks) {       // fully unrolled, static
      enc_step(ks, lds, abuf[ks & 3], acc, nlane, kq);
      if (ks < 46) enc_lda(abuf[ks & 3], wfrag, ks + 4, mtbase, lane);
    }
  }

  __syncthreads();
  float* lg = (float*)lds;
  if (wv < 7) {
    #pragma unroll
    for (int mm = 0; mm < 2; ++mm) {
      #pragma unroll
      for (int nt = 0; nt < 2; ++nt) {
        #pragma unroll
        for (int r = 0; r < 4; ++r) {
          int m  = (mtbase + mm) * 16 + kq * 4 + r;
          int px = nt * 16 + nlane;
          lg[m * 36 + px] = acc[mm][nt][r] + (m < OE_ ? b_enc[m] : 0.f);
        }
      }
    }
  }
  __syncthreads();

  if (t < 128) {
    int px = t & 31, rr = t >> 5;
    float v[49];
    float mx = -1e30f;
    #pragma unroll
    for (int n = 0; n < 49; ++n) {
      v[n] = lg[(4 * n + rr) * 36 + px];
      mx = fmaxf(mx, v[n]);
    }
    float sum = 0.f;
    #pragma unroll
    for (int n = 0; n < 49; ++n) { v[n] = __expf(v[n] - mx); sum += v[n]; }
    float inv = 1.f / sum;
    u16* so = smax + ((size_t)bh * 64 + w0 + px) * OE_;
    #pragma unroll
    for (int n = 0; n < 49; ++n) so[n * 4 + rr] = f2bf(v[n] * inv);   // [n][r] bf16
  }
}

// ------------------------------------------------------------------
// Kernel 3: CARAFE v19 — R16 v16 structure EXACTLY (unroll-1, 256 thr,
// proven 48 µs) with fp32 operands: padded xtp (no bounds checks, no
// xv unpack) + f32 ssm (no sv unpack).  Per tap: 2 b128 VMEM +
// 1 b128 LDS + 32 FMA  (~35 instr vs 46, -24%).  VGPR ~60.
// ------------------------------------------------------------------
__global__ __launch_bounds__(256) void carafe_k(
    const float* __restrict__ xtp, const u16* __restrict__ smax,
    float* __restrict__ out) {
  __shared__ __align__(16) float ssm[8 * 200];   // 6,400 B (f32)
  int t   = threadIdx.x;
  int bid = blockIdx.x;                      // 2048 blocks
  int pg  = (bid & 7) * 256 + (bid >> 3);    // bijective XCD chunk
  int wq  = pg & 7;
  int h   = (pg >> 3) & 63;
  int b   = pg >> 9;
  int w0  = wq * 8;

  // ---- stage ssm: 8 pixels x 49 quads, bf16 -> f32 ----
  for (int idx = t; idx < 392; idx += 256) {
    int pix = idx / 49, n = idx - pix * 49;
    const u16* sp = smax +
        ((size_t)((b * 64 + h) * 64) + w0 + pix) * OE_ + n * 4;
    u32x2 sv2 = *reinterpret_cast<const u32x2*>(sp);
    f32x4 sv = {__builtin_bit_cast(float, sv2[0] << 16),
                __builtin_bit_cast(float, sv2[0] & 0xffff0000u),
                __builtin_bit_cast(float, sv2[1] << 16),
                __builtin_bit_cast(float, sv2[1] & 0xffff0000u)};
    *reinterpret_cast<f32x4*>(ssm + pix * 200 + n * 4) = sv;
  }
  __syncthreads();

  int cg  = t & 31;          // channel group: c = cg*8 .. cg*8+7
  int pix = t >> 5;          // 0..7
  int w   = w0 + pix;
  const float* sb = ssm + pix * 200;
  const float* xb = xtp + ((size_t)(b * XP_) * XP_) * C_ + cg * 8;

  f32x4 acc[8];
  #pragma unroll
  for (int ci = 0; ci < 8; ++ci) acc[ci] = (f32x4){0.f, 0.f, 0.f, 0.f};

  #pragma unroll 1
  for (int dy = 0; dy < 7; ++dy) {
    const float* xrow = xb + ((size_t)(h + dy) * XP_ + w) * C_;
    #pragma unroll
    for (int dx = 0; dx < 7; ++dx) {
      f32x4 xa = *reinterpret_cast<const f32x4*>(xrow + dx * C_);
      f32x4 xc = *reinterpret_cast<const f32x4*>(xrow + dx * C_ + 4);
      f32x4 sv = *reinterpret_cast<const f32x4*>(sb + (dy * 7 + dx) * 4);
      #pragma unroll
      for (int ci = 0; ci < 4; ++ci) {
        acc[ci][0] = fmaf(xa[ci], sv[0], acc[ci][0]);
        acc[ci][1] = fmaf(xa[ci], sv[1], acc[ci][1]);
        acc[ci][2] = fmaf(xa[ci], sv[2], acc[ci][2]);
        acc[ci][3] = fmaf(xa[ci], sv[3], acc[ci][3]);
      }
      #pragma unroll
      for (int ci = 0; ci < 4; ++ci) {
        acc[4 + ci][0] = fmaf(xc[ci], sv[0], acc[4 + ci][0]);
        acc[4 + ci][1] = fmaf(xc[ci], sv[1], acc[4 + ci][1]);
        acc[4 + ci][2] = fmaf(xc[ci], sv[2], acc[4 + ci][2]);
        acc[4 + ci][3] = fmaf(xc[ci], sv[3], acc[4 + ci][3]);
      }
    }
  }

  #pragma unroll
  for (int ci = 0; ci < 8; ++ci) {
    int c = cg * 8 + ci;
    float* base = out + ((size_t)(b * C_ + c) * OH_ + 2 * h) * OW_ + 2 * w;
    *reinterpret_cast<float2*>(base)       = make_float2(acc[ci][0], acc[ci][1]);
    *reinterpret_cast<float2*>(base + OW_) = make_float2(acc[ci][2], acc[ci][3]);
  }
}

// ------------------------------------------------------------------
extern "C" void kernel_launch(void* const* d_in, const int* in_sizes, int n_in,
                              void* d_out, int out_size, void* d_ws, size_t ws_size,
                              hipStream_t stream) {
  const float* x      = (const float*)d_in[0];
  const float* w_comp = (const float*)d_in[1];
  const float* b_comp = (const float*)d_in[2];
  const float* w_enc  = (const float*)d_in[3];
  const float* b_enc  = (const float*)d_in[4];
  float* out = (float*)d_out;

  float* wct = (float*)d_ws;                    //    16,384 f32
  u16* smax  = (u16*)(wct + 16384);             // 3,211,264 bf16
  u16* wfrag = smax + 3211264;                  //   358,400 bf16
  u16* comp  = wfrag + 358400;                  // 1,048,576 bf16
  float* xtp = (float*)(comp + 1048576);        // 5,017,600 f32 (padded, ~29.4MB total)

  prep_weights<<<256, 256, 0, stream>>>(w_comp, w_enc, wct, wfrag, xtp);
  compress_k<<<B_ * H_ * 4, 256, 0, stream>>>(x, wct, b_comp, comp, xtp);
  enc_mfma_k<<<512, 512, 0, stream>>>(comp, wfrag, b_enc, smax);
  carafe_k<<<2048, 256, 0, stream>>>(xtp, smax, out);
}

// Round 21
// 120.185 us; speedup vs baseline: 1.1577x; 1.1577x over previous
//
#include <hip/hip_runtime.h>
#include <math.h>
#include <stdint.h>

#define B_   4
#define C_   256
#define H_   64
#define W_   64
#define CC_  64
#define OE_  196
#define OH_  128
#define OW_  128
#define XH_  72    // padded height for xnc (64 + 3 + up to dy=7)
#define XW_  80    // padded width  (row stride 160B, 16B-aligned)

typedef uint32_t u32;
typedef unsigned short u16;
typedef __attribute__((ext_vector_type(8))) short bf16x8;
typedef __attribute__((ext_vector_type(4))) float f32x4;
typedef __attribute__((ext_vector_type(4))) u32 u32x4;
typedef __attribute__((ext_vector_type(2))) u32 u32x2;

__device__ __forceinline__ u16 f2bf(float f) {
  u32 u = __builtin_bit_cast(u32, f);
  u32 r = (u + 0x7FFFu + ((u >> 16) & 1u)) >> 16;   // RNE
  return (u16)r;
}

// ------------------------------------------------------------------
// Kernel 0: weight re-layouts + xnc zeroing.
// ------------------------------------------------------------------
__global__ __launch_bounds__(256) void prep_weights(
    const float* __restrict__ w_comp, const float* __restrict__ w_enc,
    float* __restrict__ wct, u16* __restrict__ wfrag,
    u16* __restrict__ xnc) {
  int idx = blockIdx.x * 256 + threadIdx.x;    // 0..65535
  if (idx < 50 * 14 * 64) {
    int lane = idx & 63;
    int mt   = (idx >> 6) % 14;
    int ks   = idx / (14 * 64);
    int o    = mt * 16 + (lane & 15);
    int tap  = ks >> 1, s = ks & 1;
    int ky   = tap / 5, kx = tap % 5;
    int cb   = s * 32 + (lane >> 4) * 8;
    u32 pk[4];
    #pragma unroll
    for (int p = 0; p < 4; ++p) {
      u16 lo = 0, hi = 0;
      if (o < OE_) {
        lo = f2bf(w_enc[((o * CC_ + cb + 2 * p) * 5 + ky) * 5 + kx]);
        hi = f2bf(w_enc[((o * CC_ + cb + 2 * p + 1) * 5 + ky) * 5 + kx]);
      }
      pk[p] = (u32)lo | ((u32)hi << 16);
    }
    *reinterpret_cast<u32x4*>(wfrag + (size_t)idx * 8) =
        *reinterpret_cast<u32x4*>(pk);
  }
  if (idx < C_ * CC_) {
    int cc = idx / C_, c = idx % C_;
    wct[c * CC_ + cc] = w_comp[cc * C_ + c];
  }
  // zero all of xnc (4*256*72*80/8 = 737,280 16B chunks)
  {
    u32x4 z = {0, 0, 0, 0};
    for (int i = idx; i < B_ * C_ * XH_ * XW_ / 8; i += 65536)
      *reinterpret_cast<u32x4*>(xnc + (size_t)i * 8) = z;
  }
}

// ------------------------------------------------------------------
// Kernel 1: 1x1 compressor — comp bf16 + padded NCHW bf16 xnc
// (xnc[b][c][h+3][w+3], halo pre-zeroed).
// ------------------------------------------------------------------
__global__ __launch_bounds__(256) void compress_k(
    const float* __restrict__ x, const float* __restrict__ wct,
    const float* __restrict__ b_comp, u16* __restrict__ comp,
    u16* __restrict__ xnc) {
  __shared__ float xs[C_ * 20];
  int t   = threadIdx.x;
  int gid = blockIdx.x;
  int wq  = gid & 3;
  int bh  = gid >> 2;
  int b = bh >> 6, h = bh & 63;
  int w0 = wq * 16;

  const float* xrow = x + (size_t)b * C_ * H_ * W_ + (size_t)h * W_ + w0;
  for (int i = t; i < 1024; i += 256) {
    int c = i >> 2, q = i & 3;
    f32x4 v = *reinterpret_cast<const f32x4*>(xrow + (size_t)c * H_ * W_ + q * 4);
    *reinterpret_cast<f32x4*>(xs + c * 20 + q * 4) = v;
  }
  __syncthreads();

  int w = t & 15, cq = t >> 4;   // cq 0..15 -> 4 cc each
  float acc[4] = {0.f, 0.f, 0.f, 0.f};
  for (int c = 0; c < C_; ++c) {
    float xv = xs[c * 20 + w];
    const float* wr = wct + c * CC_ + cq * 4;
    #pragma unroll
    for (int i = 0; i < 4; ++i) acc[i] = fmaf(xv, wr[i], acc[i]);
  }
  u32 pk[2];
  #pragma unroll
  for (int p = 0; p < 2; ++p) {
    u16 lo = f2bf(acc[2 * p]     + b_comp[cq * 4 + 2 * p]);
    u16 hi = f2bf(acc[2 * p + 1] + b_comp[cq * 4 + 2 * p + 1]);
    pk[p] = (u32)lo | ((u32)hi << 16);
  }
  *reinterpret_cast<u32x2*>(comp + ((size_t)bh * 64 + w0 + w) * CC_ + cq * 4) =
      *reinterpret_cast<u32x2*>(pk);

  // ---- xnc: thread (w,cq) scatters 16 channels (coalesced in w) ----
  #pragma unroll
  for (int i = 0; i < 16; ++i) {
    int c = cq * 16 + i;
    xnc[((size_t)(b * C_ + c) * XH_ + (h + 3)) * XW_ + (w0 + w + 3)] =
        f2bf(xs[c * 20 + w]);
  }
}

// ------------------------------------------------------------------
// Kernel 2: encoder MFMA GEMM v9 (unchanged from R18).
// ------------------------------------------------------------------
#define ELG_ 32256   // 224*36*4

__device__ __forceinline__ void enc_lda(
    bf16x8 (&a)[2], const u16* __restrict__ wfrag,
    int ks, int mtbase, int lane) {
  #pragma unroll
  for (int mm = 0; mm < 2; ++mm)
    a[mm] = *reinterpret_cast<const bf16x8*>(
        wfrag + (((size_t)ks * 14 + mtbase + mm) * 64 + lane) * 8);
}

__device__ __forceinline__ void enc_step(
    int ks, const char* lds, const bf16x8 (&a)[2], f32x4 (&acc)[2][2],
    int nlane, int kq) {
  int tap = ks >> 1, s = ks & 1;
  int ky = tap / 5, kx = tap % 5;   // constants after full unroll
  bf16x8 bf[2];
  #pragma unroll
  for (int nt = 0; nt < 2; ++nt) {
    int col = nt * 16 + nlane + kx;
    int byte = (((ky * 36 + col) * 64 + s * 32 + kq * 8) * 2) ^ ((col & 7) << 4);
    bf[nt] = *reinterpret_cast<const bf16x8*>(lds + byte);
  }
  #pragma unroll
  for (int mm = 0; mm < 2; ++mm)
    #pragma unroll
    for (int nt = 0; nt < 2; ++nt)
      acc[mm][nt] = __builtin_amdgcn_mfma_f32_16x16x32_bf16(
          a[mm], bf[nt], acc[mm][nt], 0, 0, 0);
}

__global__ __launch_bounds__(512) void enc_mfma_k(
    const u16* __restrict__ comp, const u16* __restrict__ wfrag,
    const float* __restrict__ b_enc, u16* __restrict__ smax) {
  __shared__ __align__(16) char lds[ELG_];

  int t   = threadIdx.x;                   // 0..511
  int bid = blockIdx.x;
  int swz = (bid & 7) * 64 + (bid >> 3);   // 512 blocks, bijective
  int wh  = swz & 1;
  int bh  = swz >> 1;
  int b = bh >> 6, h = bh & 63;
  int w0 = wh * 32;

  {
    const u16* cbse = comp + (size_t)b * H_ * W_ * CC_;
    for (int i = t; i < 1440; i += 512) {
      int q = i & 7, colr = i >> 3;
      int col = colr % 36, r = colr / 36;
      int hh = h - 2 + r, gw = w0 - 2 + col;
      u32x4 v = {0, 0, 0, 0};
      if ((unsigned)hh < H_ && (unsigned)gw < W_)
        v = *reinterpret_cast<const u32x4*>(cbse + ((size_t)hh * W_ + gw) * CC_ + q * 8);
      int byte = ((r * 36 + col) * 128 + q * 16) ^ ((col & 7) << 4);
      *reinterpret_cast<u32x4*>(lds + byte) = v;
    }
  }
  __syncthreads();   // B ready; no further barriers in K-loop

  int wv    = __builtin_amdgcn_readfirstlane(t >> 6);   // 0..7
  int lane  = t & 63;
  int nlane = lane & 15, kq = lane >> 4;
  int mtbase = wv * 2;

  f32x4 acc[2][2];
  #pragma unroll
  for (int mm = 0; mm < 2; ++mm)
    #pragma unroll
    for (int nt = 0; nt < 2; ++nt) acc[mm][nt] = (f32x4){0.f, 0.f, 0.f, 0.f};

  if (wv < 7) {
    bf16x8 abuf[4][2];
    #pragma unroll
    for (int p = 0; p < 4; ++p) enc_lda(abuf[p], wfrag, p, mtbase, lane);
    #pragma unroll
    for (int ks = 0; ks < 50; ++ks) {       // fully unrolled, static
      enc_step(ks, lds, abuf[ks & 3], acc, nlane, kq);
      if (ks < 46) enc_lda(abuf[ks & 3], wfrag, ks + 4, mtbase, lane);
    }
  }

  __syncthreads();
  float* lg = (float*)lds;
  if (wv < 7) {
    #pragma unroll
    for (int mm = 0; mm < 2; ++mm) {
      #pragma unroll
      for (int nt = 0; nt < 2; ++nt) {
        #pragma unroll
        for (int r = 0; r < 4; ++r) {
          int m  = (mtbase + mm) * 16 + kq * 4 + r;
          int px = nt * 16 + nlane;
          lg[m * 36 + px] = acc[mm][nt][r] + (m < OE_ ? b_enc[m] : 0.f);
        }
      }
    }
  }
  __syncthreads();

  if (t < 128) {
    int px = t & 31, rr = t >> 5;
    float v[49];
    float mx = -1e30f;
    #pragma unroll
    for (int n = 0; n < 49; ++n) {
      v[n] = lg[(4 * n + rr) * 36 + px];
      mx = fmaxf(mx, v[n]);
    }
    float sum = 0.f;
    #pragma unroll
    for (int n = 0; n < 49; ++n) { v[n] = __expf(v[n] - mx); sum += v[n]; }
    float inv = 1.f / sum;
    u16* so = smax + ((size_t)bh * 64 + w0 + px) * OE_;
    #pragma unroll
    for (int n = 0; n < 49; ++n) so[n * 4 + rr] = f2bf(v[n] * inv);   // [n][r] bf16
  }
}

// ------------------------------------------------------------------
// Kernel 3: CARAFE v20 — MFMA formulation.
// Strip = (b, h, p, 8 w-pixels): C[M=256 c][N=16 = 8wi x 2q] =
//   A[c][K=128 k=(dy,dx')] x B[k][n], banded B from sv, A straight
//   from padded NCHW bf16 xnc (8 contiguous bf16 per lane = 1 b128).
// Wave = one strip; block = 4 waves sharing 16 pixels' sv in LDS.
// Per wave: 64 A-loads + 64 MFMA + B-build; acc = one f32x4 (per-mt
// sequential) -> VGPR ~60, no spill possible by construction.
// Fragment layouts identical to enc's (verified since R2).
// ------------------------------------------------------------------
__global__ __launch_bounds__(256) void carafe_k(
    const u16* __restrict__ xnc, const u16* __restrict__ smax,
    float* __restrict__ out) {
  __shared__ __align__(8) u16 svl[16 * 200];   // 6,400 B
  int t   = threadIdx.x;
  int bid = blockIdx.x;                        // 1024 blocks
  int swz = (bid & 7) * 128 + (bid >> 3);      // bijective XCD chunk
  int ws2 = swz & 3;           // which 16-pixel group
  int h   = (swz >> 2) & 63;
  int b   = swz >> 8;
  int w00 = ws2 * 16;

  // ---- stage sv for 16 pixels: 16 x 49 b64 quads ----
  for (int idx = t; idx < 784; idx += 256) {
    int pix = idx / 49, n = idx - pix * 49;
    const u16* sp = smax +
        ((size_t)((b * 64 + h) * 64) + w00 + pix) * OE_ + n * 4;
    *reinterpret_cast<u32x2*>(svl + pix * 200 + n * 4) =
        *reinterpret_cast<const u32x2*>(sp);
  }
  __syncthreads();

  int wv   = t >> 6;           // 0..3
  int lane = t & 63;
  int p    = wv >> 1;          // output row parity
  int ws   = wv & 1;           // strip within pixel group
  int w0   = w00 + ws * 8;
  const u16* svb = svl + ws * 8 * 200;

  int col = lane & 15;         // n = wi*2 + q
  int wi  = col >> 1, q = col & 1;
  int lg  = lane >> 4;         // 0..3
  int mrow = lane & 15;        // c within M-tile (A operand row)

  // ---- build banded B fragments (4 K-halves) ----
  bf16x8 bfr[4];
  #pragma unroll
  for (int ks = 0; ks < 4; ++ks) {
    short v[8];
    #pragma unroll
    for (int j = 0; j < 8; ++j) {
      int k   = ks * 32 + lg * 8 + j;
      int dy  = k >> 4, dxp = k & 15;
      int dx  = dxp - wi;
      u16 s = 0;
      if (dy < 7 && dx >= 0 && dx < 7)
        s = svb[wi * 200 + (dy * 7 + dx) * 4 + 2 * p + q];
      v[j] = (short)s;
    }
    bfr[ks] = (bf16x8){v[0], v[1], v[2], v[3], v[4], v[5], v[6], v[7]};
  }

  // ---- 16 M-tiles x 4 K-halves of MFMA ----
  const u16* xb = xnc + (size_t)(b * C_) * XH_ * XW_;
  #pragma unroll 4
  for (int mt = 0; mt < 16; ++mt) {
    int c = mt * 16 + mrow;
    f32x4 acc = {0.f, 0.f, 0.f, 0.f};
    #pragma unroll
    for (int ks = 0; ks < 4; ++ks) {
      int dy = ks * 2 + (lg >> 1);
      int wb = w0 + 8 * (lg & 1);
      bf16x8 af = *reinterpret_cast<const bf16x8*>(
          xb + ((size_t)c * XH_ + (h + dy)) * XW_ + wb);
      acc = __builtin_amdgcn_mfma_f32_16x16x32_bf16(af, bfr[ks], acc, 0, 0, 0);
    }
    // C: col = lane&15 -> ow = 2*w0 + col; row = lg*4 + reg -> c
    float* obase = out +
        ((size_t)(b * C_ + mt * 16 + lg * 4) * OH_ + (2 * h + p)) * OW_ +
        2 * w0 + col;
    obase[0]                        = acc[0];
    obase[(size_t)OH_ * OW_]        = acc[1];
    obase[2 * (size_t)OH_ * OW_]    = acc[2];
    obase[3 * (size_t)OH_ * OW_]    = acc[3];
  }
}

// ------------------------------------------------------------------
extern "C" void kernel_launch(void* const* d_in, const int* in_sizes, int n_in,
                              void* d_out, int out_size, void* d_ws, size_t ws_size,
                              hipStream_t stream) {
  const float* x      = (const float*)d_in[0];
  const float* w_comp = (const float*)d_in[1];
  const float* b_comp = (const float*)d_in[2];
  const float* w_enc  = (const float*)d_in[3];
  const float* b_enc  = (const float*)d_in[4];
  float* out = (float*)d_out;

  float* wct = (float*)d_ws;                    //    16,384 f32
  u16* smax  = (u16*)(wct + 16384);             // 3,211,264 bf16
  u16* wfrag = smax + 3211264;                  //   358,400 bf16
  u16* comp  = wfrag + 358400;                  // 1,048,576 bf16
  u16* xnc   = comp + 1048576;                  // 4*256*72*80 = 5,898,240 bf16 (~21MB)

  prep_weights<<<256, 256, 0, stream>>>(w_comp, w_enc, wct, wfrag, xnc);
  compress_k<<<B_ * H_ * 4, 256, 0, stream>>>(x, wct, b_comp, comp, xnc);
  enc_mfma_k<<<512, 512, 0, stream>>>(comp, wfrag, b_enc, smax);
  carafe_k<<<1024, 256, 0, stream>>>(xnc, smax, out);
}

// Round 22
// 113.675 us; speedup vs baseline: 1.2240x; 1.0573x over previous
//
#include <hip/hip_runtime.h>
#include <math.h>
#include <stdint.h>

#define B_   4
#define C_   256
#define H_   64
#define W_   64
#define CC_  64
#define OE_  196
#define OH_  128
#define OW_  128
#define XH_  72    // padded height for xnc
#define XW_  80    // padded width (row stride 160B)

typedef uint32_t u32;
typedef unsigned short u16;
typedef __attribute__((ext_vector_type(8))) short bf16x8;
typedef __attribute__((ext_vector_type(4))) float f32x4;
typedef __attribute__((ext_vector_type(4))) u32 u32x4;
typedef __attribute__((ext_vector_type(2))) u32 u32x2;

__device__ __forceinline__ u16 f2bf(float f) {
  u32 u = __builtin_bit_cast(u32, f);
  u32 r = (u + 0x7FFFu + ((u >> 16) & 1u)) >> 16;   // RNE
  return (u16)r;
}

// ------------------------------------------------------------------
// Kernel 0: weight re-layouts + xnc zeroing (unchanged).
// ------------------------------------------------------------------
__global__ __launch_bounds__(256) void prep_weights(
    const float* __restrict__ w_comp, const float* __restrict__ w_enc,
    float* __restrict__ wct, u16* __restrict__ wfrag,
    u16* __restrict__ xnc) {
  int idx = blockIdx.x * 256 + threadIdx.x;    // 0..65535
  if (idx < 50 * 14 * 64) {
    int lane = idx & 63;
    int mt   = (idx >> 6) % 14;
    int ks   = idx / (14 * 64);
    int o    = mt * 16 + (lane & 15);
    int tap  = ks >> 1, s = ks & 1;
    int ky   = tap / 5, kx = tap % 5;
    int cb   = s * 32 + (lane >> 4) * 8;
    u32 pk[4];
    #pragma unroll
    for (int p = 0; p < 4; ++p) {
      u16 lo = 0, hi = 0;
      if (o < OE_) {
        lo = f2bf(w_enc[((o * CC_ + cb + 2 * p) * 5 + ky) * 5 + kx]);
        hi = f2bf(w_enc[((o * CC_ + cb + 2 * p + 1) * 5 + ky) * 5 + kx]);
      }
      pk[p] = (u32)lo | ((u32)hi << 16);
    }
    *reinterpret_cast<u32x4*>(wfrag + (size_t)idx * 8) =
        *reinterpret_cast<u32x4*>(pk);
  }
  if (idx < C_ * CC_) {
    int cc = idx / C_, c = idx % C_;
    wct[c * CC_ + cc] = w_comp[cc * C_ + c];
  }
  {
    u32x4 z = {0, 0, 0, 0};
    for (int i = idx; i < B_ * C_ * XH_ * XW_ / 8; i += 65536)
      *reinterpret_cast<u32x4*>(xnc + (size_t)i * 8) = z;
  }
}

// ------------------------------------------------------------------
// Kernel 1: 1x1 compressor — comp bf16 + padded NCHW bf16 xnc.
// ------------------------------------------------------------------
__global__ __launch_bounds__(256) void compress_k(
    const float* __restrict__ x, const float* __restrict__ wct,
    const float* __restrict__ b_comp, u16* __restrict__ comp,
    u16* __restrict__ xnc) {
  __shared__ float xs[C_ * 20];
  int t   = threadIdx.x;
  int gid = blockIdx.x;
  int wq  = gid & 3;
  int bh  = gid >> 2;
  int b = bh >> 6, h = bh & 63;
  int w0 = wq * 16;

  const float* xrow = x + (size_t)b * C_ * H_ * W_ + (size_t)h * W_ + w0;
  for (int i = t; i < 1024; i += 256) {
    int c = i >> 2, q = i & 3;
    f32x4 v = *reinterpret_cast<const f32x4*>(xrow + (size_t)c * H_ * W_ + q * 4);
    *reinterpret_cast<f32x4*>(xs + c * 20 + q * 4) = v;
  }
  __syncthreads();

  int w = t & 15, cq = t >> 4;   // cq 0..15 -> 4 cc each
  float acc[4] = {0.f, 0.f, 0.f, 0.f};
  for (int c = 0; c < C_; ++c) {
    float xv = xs[c * 20 + w];
    const float* wr = wct + c * CC_ + cq * 4;
    #pragma unroll
    for (int i = 0; i < 4; ++i) acc[i] = fmaf(xv, wr[i], acc[i]);
  }
  u32 pk[2];
  #pragma unroll
  for (int p = 0; p < 2; ++p) {
    u16 lo = f2bf(acc[2 * p]     + b_comp[cq * 4 + 2 * p]);
    u16 hi = f2bf(acc[2 * p + 1] + b_comp[cq * 4 + 2 * p + 1]);
    pk[p] = (u32)lo | ((u32)hi << 16);
  }
  *reinterpret_cast<u32x2*>(comp + ((size_t)bh * 64 + w0 + w) * CC_ + cq * 4) =
      *reinterpret_cast<u32x2*>(pk);

  #pragma unroll
  for (int i = 0; i < 16; ++i) {
    int c = cq * 16 + i;
    xnc[((size_t)(b * C_ + c) * XH_ + (h + 3)) * XW_ + (w0 + w + 3)] =
        f2bf(xs[c * 20 + w]);
  }
}

// ------------------------------------------------------------------
// Kernel 2: encoder MFMA GEMM v9 (unchanged).
// ------------------------------------------------------------------
#define ELG_ 32256   // 224*36*4

__device__ __forceinline__ void enc_lda(
    bf16x8 (&a)[2], const u16* __restrict__ wfrag,
    int ks, int mtbase, int lane) {
  #pragma unroll
  for (int mm = 0; mm < 2; ++mm)
    a[mm] = *reinterpret_cast<const bf16x8*>(
        wfrag + (((size_t)ks * 14 + mtbase + mm) * 64 + lane) * 8);
}

__device__ __forceinline__ void enc_step(
    int ks, const char* lds, const bf16x8 (&a)[2], f32x4 (&acc)[2][2],
    int nlane, int kq) {
  int tap = ks >> 1, s = ks & 1;
  int ky = tap / 5, kx = tap % 5;   // constants after full unroll
  bf16x8 bf[2];
  #pragma unroll
  for (int nt = 0; nt < 2; ++nt) {
    int col = nt * 16 + nlane + kx;
    int byte = (((ky * 36 + col) * 64 + s * 32 + kq * 8) * 2) ^ ((col & 7) << 4);
    bf[nt] = *reinterpret_cast<const bf16x8*>(lds + byte);
  }
  #pragma unroll
  for (int mm = 0; mm < 2; ++mm)
    #pragma unroll
    for (int nt = 0; nt < 2; ++nt)
      acc[mm][nt] = __builtin_amdgcn_mfma_f32_16x16x32_bf16(
          a[mm], bf[nt], acc[mm][nt], 0, 0, 0);
}

__global__ __launch_bounds__(512) void enc_mfma_k(
    const u16* __restrict__ comp, const u16* __restrict__ wfrag,
    const float* __restrict__ b_enc, u16* __restrict__ smax) {
  __shared__ __align__(16) char lds[ELG_];

  int t   = threadIdx.x;                   // 0..511
  int bid = blockIdx.x;
  int swz = (bid & 7) * 64 + (bid >> 3);   // 512 blocks, bijective
  int wh  = swz & 1;
  int bh  = swz >> 1;
  int b = bh >> 6, h = bh & 63;
  int w0 = wh * 32;

  {
    const u16* cbse = comp + (size_t)b * H_ * W_ * CC_;
    for (int i = t; i < 1440; i += 512) {
      int q = i & 7, colr = i >> 3;
      int col = colr % 36, r = colr / 36;
      int hh = h - 2 + r, gw = w0 - 2 + col;
      u32x4 v = {0, 0, 0, 0};
      if ((unsigned)hh < H_ && (unsigned)gw < W_)
        v = *reinterpret_cast<const u32x4*>(cbse + ((size_t)hh * W_ + gw) * CC_ + q * 8);
      int byte = ((r * 36 + col) * 128 + q * 16) ^ ((col & 7) << 4);
      *reinterpret_cast<u32x4*>(lds + byte) = v;
    }
  }
  __syncthreads();   // B ready; no further barriers in K-loop

  int wv    = __builtin_amdgcn_readfirstlane(t >> 6);   // 0..7
  int lane  = t & 63;
  int nlane = lane & 15, kq = lane >> 4;
  int mtbase = wv * 2;

  f32x4 acc[2][2];
  #pragma unroll
  for (int mm = 0; mm < 2; ++mm)
    #pragma unroll
    for (int nt = 0; nt < 2; ++nt) acc[mm][nt] = (f32x4){0.f, 0.f, 0.f, 0.f};

  if (wv < 7) {
    bf16x8 abuf[4][2];
    #pragma unroll
    for (int p = 0; p < 4; ++p) enc_lda(abuf[p], wfrag, p, mtbase, lane);
    #pragma unroll
    for (int ks = 0; ks < 50; ++ks) {       // fully unrolled, static
      enc_step(ks, lds, abuf[ks & 3], acc, nlane, kq);
      if (ks < 46) enc_lda(abuf[ks & 3], wfrag, ks + 4, mtbase, lane);
    }
  }

  __syncthreads();
  float* lg = (float*)lds;
  if (wv < 7) {
    #pragma unroll
    for (int mm = 0; mm < 2; ++mm) {
      #pragma unroll
      for (int nt = 0; nt < 2; ++nt) {
        #pragma unroll
        for (int r = 0; r < 4; ++r) {
          int m  = (mtbase + mm) * 16 + kq * 4 + r;
          int px = nt * 16 + nlane;
          lg[m * 36 + px] = acc[mm][nt][r] + (m < OE_ ? b_enc[m] : 0.f);
        }
      }
    }
  }
  __syncthreads();

  if (t < 128) {
    int px = t & 31, rr = t >> 5;
    float v[49];
    float mx = -1e30f;
    #pragma unroll
    for (int n = 0; n < 49; ++n) {
      v[n] = lg[(4 * n + rr) * 36 + px];
      mx = fmaxf(mx, v[n]);
    }
    float sum = 0.f;
    #pragma unroll
    for (int n = 0; n < 49; ++n) { v[n] = __expf(v[n] - mx); sum += v[n]; }
    float inv = 1.f / sum;
    u16* so = smax + ((size_t)bh * 64 + w0 + px) * OE_;
    #pragma unroll
    for (int n = 0; n < 49; ++n) so[n * 4 + rr] = f2bf(v[n] * inv);   // [n][r] bf16
  }
}

// ------------------------------------------------------------------
// Kernel 3: CARAFE v21 — MFMA formulation + TLP + mt ping-pong.
// Grid 2048 (mh splits the 16 M-tiles in half -> 8 blocks/CU, 32
// waves/CU capacity).  Per wave: 8 mt, each 4 A-frag b128 + 4 MFMA;
// A-frags for mt+1 prefetched into the alternate named buffer while
// mt computes (enc-v9-proven pattern).  VGPR ~70-90.
// ------------------------------------------------------------------
__device__ __forceinline__ void carafe_lda(
    bf16x8 (&buf)[4], const u16* __restrict__ xb,
    int c, int h, int w0, int lg) {
  #pragma unroll
  for (int ks = 0; ks < 4; ++ks) {
    int dy = ks * 2 + (lg >> 1);
    int wb = w0 + 8 * (lg & 1);
    buf[ks] = *reinterpret_cast<const bf16x8*>(
        xb + ((size_t)c * XH_ + (h + dy)) * XW_ + wb);
  }
}

__global__ __launch_bounds__(256) void carafe_k(
    const u16* __restrict__ xnc, const u16* __restrict__ smax,
    float* __restrict__ out) {
  __shared__ __align__(8) u16 svl[16 * 200];   // 6,400 B
  int t   = threadIdx.x;
  int bid = blockIdx.x;                        // 2048 blocks
  int swz = (bid & 7) * 256 + (bid >> 3);      // bijective XCD chunk
  int mh  = swz & 1;           // M half: mt 0..7 or 8..15
  int ws2 = (swz >> 1) & 3;    // 16-pixel group
  int h   = (swz >> 3) & 63;
  int b   = swz >> 9;
  int w00 = ws2 * 16;

  // ---- stage sv for 16 pixels ----
  for (int idx = t; idx < 784; idx += 256) {
    int pix = idx / 49, n = idx - pix * 49;
    const u16* sp = smax +
        ((size_t)((b * 64 + h) * 64) + w00 + pix) * OE_ + n * 4;
    *reinterpret_cast<u32x2*>(svl + pix * 200 + n * 4) =
        *reinterpret_cast<const u32x2*>(sp);
  }
  __syncthreads();

  int wv   = t >> 6;           // 0..3
  int lane = t & 63;
  int p    = wv >> 1;          // output row parity
  int ws   = wv & 1;           // strip within pixel group
  int w0   = w00 + ws * 8;
  const u16* svb = svl + ws * 8 * 200;

  int col = lane & 15;         // n = wi*2 + q
  int wi  = col >> 1, q = col & 1;
  int lg  = lane >> 4;         // 0..3
  int mrow = lane & 15;

  // ---- build banded B fragments (4 K-halves) ----
  bf16x8 bfr[4];
  #pragma unroll
  for (int ks = 0; ks < 4; ++ks) {
    short v[8];
    #pragma unroll
    for (int j = 0; j < 8; ++j) {
      int k   = ks * 32 + lg * 8 + j;
      int dy  = k >> 4, dxp = k & 15;
      int dx  = dxp - wi;
      u16 s = 0;
      if (dy < 7 && dx >= 0 && dx < 7)
        s = svb[wi * 200 + (dy * 7 + dx) * 4 + 2 * p + q];
      v[j] = (short)s;
    }
    bfr[ks] = (bf16x8){v[0], v[1], v[2], v[3], v[4], v[5], v[6], v[7]};
  }

  // ---- 8 M-tiles with ping-pong A prefetch ----
  const u16* xb = xnc + (size_t)(b * C_) * XH_ * XW_;
  int mt0 = mh * 8;
  bf16x8 bufA[4], bufB[4];
  carafe_lda(bufA, xb, mt0 * 16 + mrow, h, w0, lg);

  #pragma unroll
  for (int i = 0; i < 8; ++i) {
    int mt = mt0 + i;
    if (i < 7) {
      if (i & 1) carafe_lda(bufA, xb, (mt + 1) * 16 + mrow, h, w0, lg);
      else       carafe_lda(bufB, xb, (mt + 1) * 16 + mrow, h, w0, lg);
    }
    f32x4 acc = {0.f, 0.f, 0.f, 0.f};
    #pragma unroll
    for (int ks = 0; ks < 4; ++ks) {
      bf16x8 af = (i & 1) ? bufB[ks] : bufA[ks];
      acc = __builtin_amdgcn_mfma_f32_16x16x32_bf16(af, bfr[ks], acc, 0, 0, 0);
    }
    float* obase = out +
        ((size_t)(b * C_ + mt * 16 + lg * 4) * OH_ + (2 * h + p)) * OW_ +
        2 * w0 + col;
    obase[0]                     = acc[0];
    obase[(size_t)OH_ * OW_]     = acc[1];
    obase[2 * (size_t)OH_ * OW_] = acc[2];
    obase[3 * (size_t)OH_ * OW_] = acc[3];
  }
}

// ------------------------------------------------------------------
extern "C" void kernel_launch(void* const* d_in, const int* in_sizes, int n_in,
                              void* d_out, int out_size, void* d_ws, size_t ws_size,
                              hipStream_t stream) {
  const float* x      = (const float*)d_in[0];
  const float* w_comp = (const float*)d_in[1];
  const float* b_comp = (const float*)d_in[2];
  const float* w_enc  = (const float*)d_in[3];
  const float* b_enc  = (const float*)d_in[4];
  float* out = (float*)d_out;

  float* wct = (float*)d_ws;                    //    16,384 f32
  u16* smax  = (u16*)(wct + 16384);             // 3,211,264 bf16
  u16* wfrag = smax + 3211264;                  //   358,400 bf16
  u16* comp  = wfrag + 358400;                  // 1,048,576 bf16
  u16* xnc   = comp + 1048576;                  // 5,898,240 bf16

  prep_weights<<<256, 256, 0, stream>>>(w_comp, w_enc, wct, wfrag, xnc);
  compress_k<<<B_ * H_ * 4, 256, 0, stream>>>(x, wct, b_comp, comp, xnc);
  enc_mfma_k<<<512, 512, 0, stream>>>(comp, wfrag, b_enc, smax);
  carafe_k<<<2048, 256, 0, stream>>>(xnc, smax, out);
}

// Round 23
// 96.305 us; speedup vs baseline: 1.4448x; 1.1804x over previous
//
#include <hip/hip_runtime.h>
#include <math.h>
#include <stdint.h>

#define B_   4
#define C_   256
#define H_   64
#define W_   64
#define CC_  64
#define OE_  196
#define OH_  128
#define OW_  128
#define XH_  72    // padded height
#define NWB_ 10    // 80 padded cols / 8

typedef uint32_t u32;
typedef unsigned short u16;
typedef __attribute__((ext_vector_type(8))) short bf16x8;
typedef __attribute__((ext_vector_type(4))) float f32x4;
typedef __attribute__((ext_vector_type(4))) u32 u32x4;
typedef __attribute__((ext_vector_type(2))) u32 u32x2;

__device__ __forceinline__ u16 f2bf(float f) {
  u32 u = __builtin_bit_cast(u32, f);
  u32 r = (u + 0x7FFFu + ((u >> 16) & 1u)) >> 16;   // RNE
  return (u16)r;
}

// ------------------------------------------------------------------
// Kernel 0: weight re-layouts + xw8 zeroing.
// ------------------------------------------------------------------
__global__ __launch_bounds__(256) void prep_weights(
    const float* __restrict__ w_comp, const float* __restrict__ w_enc,
    float* __restrict__ wct, u16* __restrict__ wfrag,
    u16* __restrict__ xw8) {
  int idx = blockIdx.x * 256 + threadIdx.x;    // 0..65535
  if (idx < 50 * 14 * 64) {
    int lane = idx & 63;
    int mt   = (idx >> 6) % 14;
    int ks   = idx / (14 * 64);
    int o    = mt * 16 + (lane & 15);
    int tap  = ks >> 1, s = ks & 1;
    int ky   = tap / 5, kx = tap % 5;
    int cb   = s * 32 + (lane >> 4) * 8;
    u32 pk[4];
    #pragma unroll
    for (int p = 0; p < 4; ++p) {
      u16 lo = 0, hi = 0;
      if (o < OE_) {
        lo = f2bf(w_enc[((o * CC_ + cb + 2 * p) * 5 + ky) * 5 + kx]);
        hi = f2bf(w_enc[((o * CC_ + cb + 2 * p + 1) * 5 + ky) * 5 + kx]);
      }
      pk[p] = (u32)lo | ((u32)hi << 16);
    }
    *reinterpret_cast<u32x4*>(wfrag + (size_t)idx * 8) =
        *reinterpret_cast<u32x4*>(pk);
  }
  if (idx < C_ * CC_) {
    int cc = idx / C_, c = idx % C_;
    wct[c * CC_ + cc] = w_comp[cc * C_ + c];
  }
  {
    u32x4 z = {0, 0, 0, 0};
    for (int i = idx; i < B_ * XH_ * NWB_ * C_; i += 65536)
      *reinterpret_cast<u32x4*>(xw8 + (size_t)i * 8) = z;
  }
}

// ------------------------------------------------------------------
// Kernel 1: 1x1 compressor — comp bf16 + xw8[b][h'][wb][c][8] bf16.
// ------------------------------------------------------------------
__global__ __launch_bounds__(256) void compress_k(
    const float* __restrict__ x, const float* __restrict__ wct,
    const float* __restrict__ b_comp, u16* __restrict__ comp,
    u16* __restrict__ xw8) {
  __shared__ float xs[C_ * 20];
  int t   = threadIdx.x;
  int gid = blockIdx.x;
  int wq  = gid & 3;
  int bh  = gid >> 2;
  int b = bh >> 6, h = bh & 63;
  int w0 = wq * 16;

  const float* xrow = x + (size_t)b * C_ * H_ * W_ + (size_t)h * W_ + w0;
  for (int i = t; i < 1024; i += 256) {
    int c = i >> 2, q = i & 3;
    f32x4 v = *reinterpret_cast<const f32x4*>(xrow + (size_t)c * H_ * W_ + q * 4);
    *reinterpret_cast<f32x4*>(xs + c * 20 + q * 4) = v;
  }
  __syncthreads();

  int w = t & 15, cq = t >> 4;   // cq 0..15 -> 4 cc each
  float acc[4] = {0.f, 0.f, 0.f, 0.f};
  for (int c = 0; c < C_; ++c) {
    float xv = xs[c * 20 + w];
    const float* wr = wct + c * CC_ + cq * 4;
    #pragma unroll
    for (int i = 0; i < 4; ++i) acc[i] = fmaf(xv, wr[i], acc[i]);
  }
  u32 pk[2];
  #pragma unroll
  for (int p = 0; p < 2; ++p) {
    u16 lo = f2bf(acc[2 * p]     + b_comp[cq * 4 + 2 * p]);
    u16 hi = f2bf(acc[2 * p + 1] + b_comp[cq * 4 + 2 * p + 1]);
    pk[p] = (u32)lo | ((u32)hi << 16);
  }
  *reinterpret_cast<u32x2*>(comp + ((size_t)bh * 64 + w0 + w) * CC_ + cq * 4) =
      *reinterpret_cast<u32x2*>(pk);

  // ---- xw8: pixel (h,w) -> h'=h+3, wp=w0+w+3, wb=wp>>3, e=wp&7 ----
  {
    int wp = w0 + w + 3;
    size_t base = (((size_t)(b * XH_ + h + 3)) * NWB_ + (wp >> 3)) * (C_ * 8) + (wp & 7);
    #pragma unroll
    for (int i = 0; i < 16; ++i) {
      int c = cq * 16 + i;
      xw8[base + c * 8] = f2bf(xs[c * 20 + w]);
    }
  }
}

// ------------------------------------------------------------------
// Kernel 2: encoder MFMA GEMM v9 (unchanged).
// ------------------------------------------------------------------
#define ELG_ 32256   // 224*36*4

__device__ __forceinline__ void enc_lda(
    bf16x8 (&a)[2], const u16* __restrict__ wfrag,
    int ks, int mtbase, int lane) {
  #pragma unroll
  for (int mm = 0; mm < 2; ++mm)
    a[mm] = *reinterpret_cast<const bf16x8*>(
        wfrag + (((size_t)ks * 14 + mtbase + mm) * 64 + lane) * 8);
}

__device__ __forceinline__ void enc_step(
    int ks, const char* lds, const bf16x8 (&a)[2], f32x4 (&acc)[2][2],
    int nlane, int kq) {
  int tap = ks >> 1, s = ks & 1;
  int ky = tap / 5, kx = tap % 5;   // constants after full unroll
  bf16x8 bf[2];
  #pragma unroll
  for (int nt = 0; nt < 2; ++nt) {
    int col = nt * 16 + nlane + kx;
    int byte = (((ky * 36 + col) * 64 + s * 32 + kq * 8) * 2) ^ ((col & 7) << 4);
    bf[nt] = *reinterpret_cast<const bf16x8*>(lds + byte);
  }
  #pragma unroll
  for (int mm = 0; mm < 2; ++mm)
    #pragma unroll
    for (int nt = 0; nt < 2; ++nt)
      acc[mm][nt] = __builtin_amdgcn_mfma_f32_16x16x32_bf16(
          a[mm], bf[nt], acc[mm][nt], 0, 0, 0);
}

__global__ __launch_bounds__(512) void enc_mfma_k(
    const u16* __restrict__ comp, const u16* __restrict__ wfrag,
    const float* __restrict__ b_enc, u16* __restrict__ smax) {
  __shared__ __align__(16) char lds[ELG_];

  int t   = threadIdx.x;                   // 0..511
  int bid = blockIdx.x;
  int swz = (bid & 7) * 64 + (bid >> 3);   // 512 blocks, bijective
  int wh  = swz & 1;
  int bh  = swz >> 1;
  int b = bh >> 6, h = bh & 63;
  int w0 = wh * 32;

  {
    const u16* cbse = comp + (size_t)b * H_ * W_ * CC_;
    for (int i = t; i < 1440; i += 512) {
      int q = i & 7, colr = i >> 3;
      int col = colr % 36, r = colr / 36;
      int hh = h - 2 + r, gw = w0 - 2 + col;
      u32x4 v = {0, 0, 0, 0};
      if ((unsigned)hh < H_ && (unsigned)gw < W_)
        v = *reinterpret_cast<const u32x4*>(cbse + ((size_t)hh * W_ + gw) * CC_ + q * 8);
      int byte = ((r * 36 + col) * 128 + q * 16) ^ ((col & 7) << 4);
      *reinterpret_cast<u32x4*>(lds + byte) = v;
    }
  }
  __syncthreads();   // B ready; no further barriers in K-loop

  int wv    = __builtin_amdgcn_readfirstlane(t >> 6);   // 0..7
  int lane  = t & 63;
  int nlane = lane & 15, kq = lane >> 4;
  int mtbase = wv * 2;

  f32x4 acc[2][2];
  #pragma unroll
  for (int mm = 0; mm < 2; ++mm)
    #pragma unroll
    for (int nt = 0; nt < 2; ++nt) acc[mm][nt] = (f32x4){0.f, 0.f, 0.f, 0.f};

  if (wv < 7) {
    bf16x8 abuf[4][2];
    #pragma unroll
    for (int p = 0; p < 4; ++p) enc_lda(abuf[p], wfrag, p, mtbase, lane);
    #pragma unroll
    for (int ks = 0; ks < 50; ++ks) {       // fully unrolled, static
      enc_step(ks, lds, abuf[ks & 3], acc, nlane, kq);
      if (ks < 46) enc_lda(abuf[ks & 3], wfrag, ks + 4, mtbase, lane);
    }
  }

  __syncthreads();
  float* lg = (float*)lds;
  if (wv < 7) {
    #pragma unroll
    for (int mm = 0; mm < 2; ++mm) {
      #pragma unroll
      for (int nt = 0; nt < 2; ++nt) {
        #pragma unroll
        for (int r = 0; r < 4; ++r) {
          int m  = (mtbase + mm) * 16 + kq * 4 + r;
          int px = nt * 16 + nlane;
          lg[m * 36 + px] = acc[mm][nt][r] + (m < OE_ ? b_enc[m] : 0.f);
        }
      }
    }
  }
  __syncthreads();

  if (t < 128) {
    int px = t & 31, rr = t >> 5;
    float v[49];
    float mx = -1e30f;
    #pragma unroll
    for (int n = 0; n < 49; ++n) {
      v[n] = lg[(4 * n + rr) * 36 + px];
      mx = fmaxf(mx, v[n]);
    }
    float sum = 0.f;
    #pragma unroll
    for (int n = 0; n < 49; ++n) { v[n] = __expf(v[n] - mx); sum += v[n]; }
    float inv = 1.f / sum;
    u16* so = smax + ((size_t)bh * 64 + w0 + px) * OE_;
    #pragma unroll
    for (int n = 0; n < 49; ++n) so[n * 4 + rr] = f2bf(v[n] * inv);   // [n][r] bf16
  }
}

// ------------------------------------------------------------------
// Kernel 3: CARAFE v22 — MFMA + coalesced A (xw8 layout: per lg-
// quarter the 16 mrow lanes read one contiguous 256B segment) +
// in-wave p-sharing (each A-frag feeds 2 MFMA).  Wave = (ws, mq):
// 4 mt x {4 A b128 + 8 MFMA + 8 stores}; mt ping-pong retained.
// ------------------------------------------------------------------
__device__ __forceinline__ void carafe_lda(
    bf16x8 (&buf)[4], const u16* __restrict__ xb,
    int c, int h, int wb0, int lg) {
  #pragma unroll
  for (int ks = 0; ks < 4; ++ks) {
    int dy = ks * 2 + (lg >> 1);
    buf[ks] = *reinterpret_cast<const bf16x8*>(
        xb + (((size_t)(h + dy)) * NWB_ + wb0 + (lg & 1)) * (C_ * 8) + c * 8);
  }
}

__global__ __launch_bounds__(256) void carafe_k(
    const u16* __restrict__ xw8, const u16* __restrict__ smax,
    float* __restrict__ out) {
  __shared__ __align__(8) u16 svl[16 * 200];   // 6,400 B
  int t   = threadIdx.x;
  int bid = blockIdx.x;                        // 2048 blocks
  int swz = (bid & 7) * 256 + (bid >> 3);      // bijective XCD chunk
  int mh  = swz & 1;           // M half
  int ws2 = (swz >> 1) & 3;    // 16-pixel group
  int h   = (swz >> 3) & 63;
  int b   = swz >> 9;
  int w00 = ws2 * 16;

  // ---- stage sv for 16 pixels ----
  for (int idx = t; idx < 784; idx += 256) {
    int pix = idx / 49, n = idx - pix * 49;
    const u16* sp = smax +
        ((size_t)((b * 64 + h) * 64) + w00 + pix) * OE_ + n * 4;
    *reinterpret_cast<u32x2*>(svl + pix * 200 + n * 4) =
        *reinterpret_cast<const u32x2*>(sp);
  }
  __syncthreads();

  int wv   = t >> 6;           // 0..3
  int lane = t & 63;
  int ws   = wv & 1;           // strip within pixel group
  int mq   = wv >> 1;          // M quarter within half
  int w0   = w00 + ws * 8;
  int wb0  = w0 >> 3;
  const u16* svb = svl + ws * 8 * 200;

  int col = lane & 15;         // n = wi*2 + q
  int wi  = col >> 1, q = col & 1;
  int lg  = lane >> 4;         // 0..3
  int mrow = lane & 15;

  // ---- build banded B fragments for BOTH p ----
  bf16x8 bfr[2][4];
  #pragma unroll
  for (int p = 0; p < 2; ++p) {
    #pragma unroll
    for (int ks = 0; ks < 4; ++ks) {
      short v[8];
      #pragma unroll
      for (int j = 0; j < 8; ++j) {
        int k   = ks * 32 + lg * 8 + j;
        int dy  = k >> 4, dxp = k & 15;
        int dx  = dxp - wi;
        u16 s = 0;
        if (dy < 7 && dx >= 0 && dx < 7)
          s = svb[wi * 200 + (dy * 7 + dx) * 4 + 2 * p + q];
        v[j] = (short)s;
      }
      bfr[p][ks] = (bf16x8){v[0], v[1], v[2], v[3], v[4], v[5], v[6], v[7]};
    }
  }

  // ---- 4 M-tiles with ping-pong A prefetch, both p per A-frag ----
  const u16* xb = xw8 + (size_t)b * XH_ * NWB_ * (C_ * 8);
  int mt0 = mh * 8 + mq * 4;
  bf16x8 bufA[4], bufB[4];
  carafe_lda(bufA, xb, mt0 * 16 + mrow, h, wb0, lg);

  #pragma unroll
  for (int i = 0; i < 4; ++i) {
    int mt = mt0 + i;
    if (i < 3) {
      if (i & 1) carafe_lda(bufA, xb, (mt + 1) * 16 + mrow, h, wb0, lg);
      else       carafe_lda(bufB, xb, (mt + 1) * 16 + mrow, h, wb0, lg);
    }
    f32x4 acc0 = {0.f, 0.f, 0.f, 0.f};
    f32x4 acc1 = {0.f, 0.f, 0.f, 0.f};
    #pragma unroll
    for (int ks = 0; ks < 4; ++ks) {
      bf16x8 af = (i & 1) ? bufB[ks] : bufA[ks];
      acc0 = __builtin_amdgcn_mfma_f32_16x16x32_bf16(af, bfr[0][ks], acc0, 0, 0, 0);
      acc1 = __builtin_amdgcn_mfma_f32_16x16x32_bf16(af, bfr[1][ks], acc1, 0, 0, 0);
    }
    float* o0 = out +
        ((size_t)(b * C_ + mt * 16 + lg * 4) * OH_ + 2 * h) * OW_ + 2 * w0 + col;
    o0[0]                     = acc0[0];
    o0[(size_t)OH_ * OW_]     = acc0[1];
    o0[2 * (size_t)OH_ * OW_] = acc0[2];
    o0[3 * (size_t)OH_ * OW_] = acc0[3];
    float* o1 = o0 + OW_;
    o1[0]                     = acc1[0];
    o1[(size_t)OH_ * OW_]     = acc1[1];
    o1[2 * (size_t)OH_ * OW_] = acc1[2];
    o1[3 * (size_t)OH_ * OW_] = acc1[3];
  }
}

// ------------------------------------------------------------------
extern "C" void kernel_launch(void* const* d_in, const int* in_sizes, int n_in,
                              void* d_out, int out_size, void* d_ws, size_t ws_size,
                              hipStream_t stream) {
  const float* x      = (const float*)d_in[0];
  const float* w_comp = (const float*)d_in[1];
  const float* b_comp = (const float*)d_in[2];
  const float* w_enc  = (const float*)d_in[3];
  const float* b_enc  = (const float*)d_in[4];
  float* out = (float*)d_out;

  float* wct = (float*)d_ws;                    //    16,384 f32
  u16* smax  = (u16*)(wct + 16384);             // 3,211,264 bf16
  u16* wfrag = smax + 3211264;                  //   358,400 bf16
  u16* comp  = wfrag + 358400;                  // 1,048,576 bf16
  u16* xw8   = comp + 1048576;                  // 4*72*10*256*8 = 5,898,240 bf16

  prep_weights<<<256, 256, 0, stream>>>(w_comp, w_enc, wct, wfrag, xw8);
  compress_k<<<B_ * H_ * 4, 256, 0, stream>>>(x, wct, b_comp, comp, xw8);
  enc_mfma_k<<<512, 512, 0, stream>>>(comp, wfrag, b_enc, smax);
  carafe_k<<<2048, 256, 0, stream>>>(xw8, smax, out);
}

// Round 24
// 69.561 us; speedup vs baseline: 2.0003x; 1.3845x over previous
//
#include <hip/hip_runtime.h>
#include <math.h>
#include <stdint.h>

#define B_   4
#define C_   256
#define H_   64
#define W_   64
#define CC_  64
#define OE_  196
#define OH_  128
#define OW_  128
#define XH_  72    // padded height
#define NWB_ 10    // 80 padded cols / 8

typedef uint32_t u32;
typedef unsigned short u16;
typedef __attribute__((ext_vector_type(8))) short bf16x8;
typedef __attribute__((ext_vector_type(4))) float f32x4;
typedef __attribute__((ext_vector_type(4))) u32 u32x4;
typedef __attribute__((ext_vector_type(2))) u32 u32x2;

__device__ __forceinline__ u16 f2bf(float f) {
  u32 u = __builtin_bit_cast(u32, f);
  u32 r = (u + 0x7FFFu + ((u >> 16) & 1u)) >> 16;   // RNE
  return (u16)r;
}

// ------------------------------------------------------------------
// Kernel 0: weight re-layouts + xw8 zeroing.
//  wfrag: enc A-fragments (unchanged).
//  wcf[ks(8)][mt(4)][lane(64)][j(8)]: compress A-fragments:
//    o = mt*16+(lane&15) (cc), c = ks*32+(lane>>4)*8+j, val=w_comp[o][c]
// ------------------------------------------------------------------
__global__ __launch_bounds__(256) void prep_weights(
    const float* __restrict__ w_comp, const float* __restrict__ w_enc,
    u16* __restrict__ wfrag, u16* __restrict__ wcf,
    u16* __restrict__ xw8) {
  int idx = blockIdx.x * 256 + threadIdx.x;    // 0..65535
  if (idx < 50 * 14 * 64) {
    int lane = idx & 63;
    int mt   = (idx >> 6) % 14;
    int ks   = idx / (14 * 64);
    int o    = mt * 16 + (lane & 15);
    int tap  = ks >> 1, s = ks & 1;
    int ky   = tap / 5, kx = tap % 5;
    int cb   = s * 32 + (lane >> 4) * 8;
    u32 pk[4];
    #pragma unroll
    for (int p = 0; p < 4; ++p) {
      u16 lo = 0, hi = 0;
      if (o < OE_) {
        lo = f2bf(w_enc[((o * CC_ + cb + 2 * p) * 5 + ky) * 5 + kx]);
        hi = f2bf(w_enc[((o * CC_ + cb + 2 * p + 1) * 5 + ky) * 5 + kx]);
      }
      pk[p] = (u32)lo | ((u32)hi << 16);
    }
    *reinterpret_cast<u32x4*>(wfrag + (size_t)idx * 8) =
        *reinterpret_cast<u32x4*>(pk);
  }
  if (idx < 8 * 4 * 64) {                      // wcf: 2048 chunks
    int lane = idx & 63;
    int mt   = (idx >> 6) & 3;
    int ks   = idx >> 8;
    int o    = mt * 16 + (lane & 15);
    int cb   = ks * 32 + (lane >> 4) * 8;
    u32 pk[4];
    #pragma unroll
    for (int p = 0; p < 4; ++p) {
      u16 lo = f2bf(w_comp[o * C_ + cb + 2 * p]);
      u16 hi = f2bf(w_comp[o * C_ + cb + 2 * p + 1]);
      pk[p] = (u32)lo | ((u32)hi << 16);
    }
    *reinterpret_cast<u32x4*>(wcf + (size_t)idx * 8) =
        *reinterpret_cast<u32x4*>(pk);
  }
  {
    u32x4 z = {0, 0, 0, 0};
    for (int i = idx; i < B_ * XH_ * NWB_ * C_; i += 65536)
      *reinterpret_cast<u32x4*>(xw8 + (size_t)i * 8) = z;
  }
}

// ------------------------------------------------------------------
// Kernel 1: 1x1 compressor via MFMA.  Block (b,h,16w): stage
// xs[256][20] f32; wave mt: B-frags built from LDS (8 b32 + cvt per
// ks), 8 A-frags (wcf, L2-hot) loaded upfront; 8 MFMA; epilogue
// bias + bf16 -> comp[pixel][cc].  xw8 write unchanged.
// ------------------------------------------------------------------
__global__ __launch_bounds__(256) void compress_k(
    const float* __restrict__ x, const u16* __restrict__ wcf,
    const float* __restrict__ b_comp, u16* __restrict__ comp,
    u16* __restrict__ xw8) {
  __shared__ float xs[C_ * 20];
  int t   = threadIdx.x;
  int gid = blockIdx.x;
  int wq  = gid & 3;
  int bh  = gid >> 2;
  int b = bh >> 6, h = bh & 63;
  int w0 = wq * 16;

  const float* xrow = x + (size_t)b * C_ * H_ * W_ + (size_t)h * W_ + w0;
  for (int i = t; i < 1024; i += 256) {
    int c = i >> 2, q = i & 3;
    f32x4 v = *reinterpret_cast<const f32x4*>(xrow + (size_t)c * H_ * W_ + q * 4);
    *reinterpret_cast<f32x4*>(xs + c * 20 + q * 4) = v;
  }
  __syncthreads();

  int wv   = __builtin_amdgcn_readfirstlane(t >> 6);   // mt 0..3
  int lane = t & 63;
  int w    = lane & 15;          // pixel within 16-w group
  int lg   = lane >> 4;          // 0..3

  // ---- A-frags: 8 K-steps, all in flight (32KB L2-hot) ----
  bf16x8 af[8];
  #pragma unroll
  for (int ks = 0; ks < 8; ++ks)
    af[ks] = *reinterpret_cast<const bf16x8*>(
        wcf + (((size_t)ks * 4 + wv) * 64 + lane) * 8);

  // ---- K-loop: build B from xs, MFMA ----
  f32x4 acc = {0.f, 0.f, 0.f, 0.f};
  #pragma unroll
  for (int ks = 0; ks < 8; ++ks) {
    short vv[8];
    #pragma unroll
    for (int j = 0; j < 8; ++j)
      vv[j] = (short)f2bf(xs[(ks * 32 + lg * 8 + j) * 20 + w]);
    bf16x8 bf = (bf16x8){vv[0], vv[1], vv[2], vv[3], vv[4], vv[5], vv[6], vv[7]};
    acc = __builtin_amdgcn_mfma_f32_16x16x32_bf16(af[ks], bf, acc, 0, 0, 0);
  }

  // ---- epilogue: bias + bf16, comp[pixel][cc] (4 cc per lane) ----
  {
    int cc0 = wv * 16 + lg * 4;
    f32x4 bias = *reinterpret_cast<const f32x4*>(b_comp + cc0);
    u32 p0 = (u32)f2bf(acc[0] + bias[0]) | ((u32)f2bf(acc[1] + bias[1]) << 16);
    u32 p1 = (u32)f2bf(acc[2] + bias[2]) | ((u32)f2bf(acc[3] + bias[3]) << 16);
    u32x2 pk = {p0, p1};
    *reinterpret_cast<u32x2*>(comp + ((size_t)bh * 64 + w0 + w) * CC_ + cc0) = pk;
  }

  // ---- xw8: thread (w16 = t&15, cq = t>>4) as before ----
  {
    int ww = t & 15, cq = t >> 4;
    int wp = w0 + ww + 3;
    size_t base = (((size_t)(b * XH_ + h + 3)) * NWB_ + (wp >> 3)) * (C_ * 8) + (wp & 7);
    #pragma unroll
    for (int i = 0; i < 16; ++i) {
      int c = cq * 16 + i;
      xw8[base + c * 8] = f2bf(xs[c * 20 + ww]);
    }
  }
}

// ------------------------------------------------------------------
// Kernel 2: encoder MFMA GEMM v9 (unchanged).
// ------------------------------------------------------------------
#define ELG_ 32256   // 224*36*4

__device__ __forceinline__ void enc_lda(
    bf16x8 (&a)[2], const u16* __restrict__ wfrag,
    int ks, int mtbase, int lane) {
  #pragma unroll
  for (int mm = 0; mm < 2; ++mm)
    a[mm] = *reinterpret_cast<const bf16x8*>(
        wfrag + (((size_t)ks * 14 + mtbase + mm) * 64 + lane) * 8);
}

__device__ __forceinline__ void enc_step(
    int ks, const char* lds, const bf16x8 (&a)[2], f32x4 (&acc)[2][2],
    int nlane, int kq) {
  int tap = ks >> 1, s = ks & 1;
  int ky = tap / 5, kx = tap % 5;   // constants after full unroll
  bf16x8 bf[2];
  #pragma unroll
  for (int nt = 0; nt < 2; ++nt) {
    int col = nt * 16 + nlane + kx;
    int byte = (((ky * 36 + col) * 64 + s * 32 + kq * 8) * 2) ^ ((col & 7) << 4);
    bf[nt] = *reinterpret_cast<const bf16x8*>(lds + byte);
  }
  #pragma unroll
  for (int mm = 0; mm < 2; ++mm)
    #pragma unroll
    for (int nt = 0; nt < 2; ++nt)
      acc[mm][nt] = __builtin_amdgcn_mfma_f32_16x16x32_bf16(
          a[mm], bf[nt], acc[mm][nt], 0, 0, 0);
}

__global__ __launch_bounds__(512) void enc_mfma_k(
    const u16* __restrict__ comp, const u16* __restrict__ wfrag,
    const float* __restrict__ b_enc, u16* __restrict__ smax) {
  __shared__ __align__(16) char lds[ELG_];

  int t   = threadIdx.x;                   // 0..511
  int bid = blockIdx.x;
  int swz = (bid & 7) * 64 + (bid >> 3);   // 512 blocks, bijective
  int wh  = swz & 1;
  int bh  = swz >> 1;
  int b = bh >> 6, h = bh & 63;
  int w0 = wh * 32;

  {
    const u16* cbse = comp + (size_t)b * H_ * W_ * CC_;
    for (int i = t; i < 1440; i += 512) {
      int q = i & 7, colr = i >> 3;
      int col = colr % 36, r = colr / 36;
      int hh = h - 2 + r, gw = w0 - 2 + col;
      u32x4 v = {0, 0, 0, 0};
      if ((unsigned)hh < H_ && (unsigned)gw < W_)
        v = *reinterpret_cast<const u32x4*>(cbse + ((size_t)hh * W_ + gw) * CC_ + q * 8);
      int byte = ((r * 36 + col) * 128 + q * 16) ^ ((col & 7) << 4);
      *reinterpret_cast<u32x4*>(lds + byte) = v;
    }
  }
  __syncthreads();   // B ready; no further barriers in K-loop

  int wv    = __builtin_amdgcn_readfirstlane(t >> 6);   // 0..7
  int lane  = t & 63;
  int nlane = lane & 15, kq = lane >> 4;
  int mtbase = wv * 2;

  f32x4 acc[2][2];
  #pragma unroll
  for (int mm = 0; mm < 2; ++mm)
    #pragma unroll
    for (int nt = 0; nt < 2; ++nt) acc[mm][nt] = (f32x4){0.f, 0.f, 0.f, 0.f};

  if (wv < 7) {
    bf16x8 abuf[4][2];
    #pragma unroll
    for (int p = 0; p < 4; ++p) enc_lda(abuf[p], wfrag, p, mtbase, lane);
    #pragma unroll
    for (int ks = 0; ks < 50; ++ks) {       // fully unrolled, static
      enc_step(ks, lds, abuf[ks & 3], acc, nlane, kq);
      if (ks < 46) enc_lda(abuf[ks & 3], wfrag, ks + 4, mtbase, lane);
    }
  }

  __syncthreads();
  float* lg = (float*)lds;
  if (wv < 7) {
    #pragma unroll
    for (int mm = 0; mm < 2; ++mm) {
      #pragma unroll
      for (int nt = 0; nt < 2; ++nt) {
        #pragma unroll
        for (int r = 0; r < 4; ++r) {
          int m  = (mtbase + mm) * 16 + kq * 4 + r;
          int px = nt * 16 + nlane;
          lg[m * 36 + px] = acc[mm][nt][r] + (m < OE_ ? b_enc[m] : 0.f);
        }
      }
    }
  }
  __syncthreads();

  if (t < 128) {
    int px = t & 31, rr = t >> 5;
    float v[49];
    float mx = -1e30f;
    #pragma unroll
    for (int n = 0; n < 49; ++n) {
      v[n] = lg[(4 * n + rr) * 36 + px];
      mx = fmaxf(mx, v[n]);
    }
    float sum = 0.f;
    #pragma unroll
    for (int n = 0; n < 49; ++n) { v[n] = __expf(v[n] - mx); sum += v[n]; }
    float inv = 1.f / sum;
    u16* so = smax + ((size_t)bh * 64 + w0 + px) * OE_;
    #pragma unroll
    for (int n = 0; n < 49; ++n) so[n * 4 + rr] = f2bf(v[n] * inv);   // [n][r] bf16
  }
}

// ------------------------------------------------------------------
// Kernel 3: CARAFE v22 (unchanged from R23): MFMA + coalesced xw8 A +
// in-wave p-sharing + mt ping-pong.
// ------------------------------------------------------------------
__device__ __forceinline__ void carafe_lda(
    bf16x8 (&buf)[4], const u16* __restrict__ xb,
    int c, int h, int wb0, int lg) {
  #pragma unroll
  for (int ks = 0; ks < 4; ++ks) {
    int dy = ks * 2 + (lg >> 1);
    buf[ks] = *reinterpret_cast<const bf16x8*>(
        xb + (((size_t)(h + dy)) * NWB_ + wb0 + (lg & 1)) * (C_ * 8) + c * 8);
  }
}

__global__ __launch_bounds__(256) void carafe_k(
    const u16* __restrict__ xw8, const u16* __restrict__ smax,
    float* __restrict__ out) {
  __shared__ __align__(8) u16 svl[16 * 200];   // 6,400 B
  int t   = threadIdx.x;
  int bid = blockIdx.x;                        // 2048 blocks
  int swz = (bid & 7) * 256 + (bid >> 3);      // bijective XCD chunk
  int mh  = swz & 1;           // M half
  int ws2 = (swz >> 1) & 3;    // 16-pixel group
  int h   = (swz >> 3) & 63;
  int b   = swz >> 9;
  int w00 = ws2 * 16;

  for (int idx = t; idx < 784; idx += 256) {
    int pix = idx / 49, n = idx - pix * 49;
    const u16* sp = smax +
        ((size_t)((b * 64 + h) * 64) + w00 + pix) * OE_ + n * 4;
    *reinterpret_cast<u32x2*>(svl + pix * 200 + n * 4) =
        *reinterpret_cast<const u32x2*>(sp);
  }
  __syncthreads();

  int wv   = t >> 6;           // 0..3
  int lane = t & 63;
  int ws   = wv & 1;
  int mq   = wv >> 1;
  int w0   = w00 + ws * 8;
  int wb0  = w0 >> 3;
  const u16* svb = svl + ws * 8 * 200;

  int col = lane & 15;
  int wi  = col >> 1, q = col & 1;
  int lg  = lane >> 4;
  int mrow = lane & 15;

  bf16x8 bfr[2][4];
  #pragma unroll
  for (int p = 0; p < 2; ++p) {
    #pragma unroll
    for (int ks = 0; ks < 4; ++ks) {
      short v[8];
      #pragma unroll
      for (int j = 0; j < 8; ++j) {
        int k   = ks * 32 + lg * 8 + j;
        int dy  = k >> 4, dxp = k & 15;
        int dx  = dxp - wi;
        u16 s = 0;
        if (dy < 7 && dx >= 0 && dx < 7)
          s = svb[wi * 200 + (dy * 7 + dx) * 4 + 2 * p + q];
        v[j] = (short)s;
      }
      bfr[p][ks] = (bf16x8){v[0], v[1], v[2], v[3], v[4], v[5], v[6], v[7]};
    }
  }

  const u16* xb = xw8 + (size_t)b * XH_ * NWB_ * (C_ * 8);
  int mt0 = mh * 8 + mq * 4;
  bf16x8 bufA[4], bufB[4];
  carafe_lda(bufA, xb, mt0 * 16 + mrow, h, wb0, lg);

  #pragma unroll
  for (int i = 0; i < 4; ++i) {
    int mt = mt0 + i;
    if (i < 3) {
      if (i & 1) carafe_lda(bufA, xb, (mt + 1) * 16 + mrow, h, wb0, lg);
      else       carafe_lda(bufB, xb, (mt + 1) * 16 + mrow, h, wb0, lg);
    }
    f32x4 acc0 = {0.f, 0.f, 0.f, 0.f};
    f32x4 acc1 = {0.f, 0.f, 0.f, 0.f};
    #pragma unroll
    for (int ks = 0; ks < 4; ++ks) {
      bf16x8 af = (i & 1) ? bufB[ks] : bufA[ks];
      acc0 = __builtin_amdgcn_mfma_f32_16x16x32_bf16(af, bfr[0][ks], acc0, 0, 0, 0);
      acc1 = __builtin_amdgcn_mfma_f32_16x16x32_bf16(af, bfr[1][ks], acc1, 0, 0, 0);
    }
    float* o0 = out +
        ((size_t)(b * C_ + mt * 16 + lg * 4) * OH_ + 2 * h) * OW_ + 2 * w0 + col;
    o0[0]                     = acc0[0];
    o0[(size_t)OH_ * OW_]     = acc0[1];
    o0[2 * (size_t)OH_ * OW_] = acc0[2];
    o0[3 * (size_t)OH_ * OW_] = acc0[3];
    float* o1 = o0 + OW_;
    o1[0]                     = acc1[0];
    o1[(size_t)OH_ * OW_]     = acc1[1];
    o1[2 * (size_t)OH_ * OW_] = acc1[2];
    o1[3 * (size_t)OH_ * OW_] = acc1[3];
  }
}

// ------------------------------------------------------------------
extern "C" void kernel_launch(void* const* d_in, const int* in_sizes, int n_in,
                              void* d_out, int out_size, void* d_ws, size_t ws_size,
                              hipStream_t stream) {
  const float* x      = (const float*)d_in[0];
  const float* w_comp = (const float*)d_in[1];
  const float* b_comp = (const float*)d_in[2];
  const float* w_enc  = (const float*)d_in[3];
  const float* b_enc  = (const float*)d_in[4];
  float* out = (float*)d_out;

  u16* smax  = (u16*)d_ws;                      // 3,211,264 bf16
  u16* wfrag = smax + 3211264;                  //   358,400 bf16
  u16* wcf   = wfrag + 358400;                  //    16,384 bf16
  u16* comp  = wcf + 16384;                     // 1,048,576 bf16
  u16* xw8   = comp + 1048576;                  // 5,898,240 bf16 (~21MB total)

  prep_weights<<<256, 256, 0, stream>>>(w_comp, w_enc, wfrag, wcf, xw8);
  compress_k<<<B_ * H_ * 4, 256, 0, stream>>>(x, wcf, b_comp, comp, xw8);
  enc_mfma_k<<<512, 512, 0, stream>>>(comp, wfrag, b_enc, smax);
  carafe_k<<<2048, 256, 0, stream>>>(xw8, smax, out);
}

// Round 25
// 68.650 us; speedup vs baseline: 2.0269x; 1.0133x over previous
//
#include <hip/hip_runtime.h>
#include <math.h>
#include <stdint.h>

#define B_   4
#define C_   256
#define H_   64
#define W_   64
#define CC_  64
#define OE_  196
#define OH_  128
#define OW_  128
#define XH_  72    // padded height
#define NWB_ 10    // 80 padded cols / 8

typedef uint32_t u32;
typedef unsigned short u16;
typedef __attribute__((ext_vector_type(8))) short bf16x8;
typedef __attribute__((ext_vector_type(4))) float f32x4;
typedef __attribute__((ext_vector_type(4))) u32 u32x4;
typedef __attribute__((ext_vector_type(2))) u32 u32x2;

__device__ __forceinline__ u16 f2bf(float f) {
  u32 u = __builtin_bit_cast(u32, f);
  u32 r = (u + 0x7FFFu + ((u >> 16) & 1u)) >> 16;   // RNE
  return (u16)r;
}

// ------------------------------------------------------------------
// Kernel 0: weight re-layouts + HALO-ONLY xw8 zeroing (interior is
// fully overwritten by compress; halo = rows [0,3)u[67,72) all wb,
// rows [3,67) wb {0,8,9}).  1.1MB instead of 11.8MB.
// ------------------------------------------------------------------
__global__ __launch_bounds__(256) void prep_weights(
    const float* __restrict__ w_comp, const float* __restrict__ w_enc,
    u16* __restrict__ wfrag, u16* __restrict__ wcf,
    u16* __restrict__ xw8) {
  int idx = blockIdx.x * 256 + threadIdx.x;    // 0..65535
  if (idx < 50 * 14 * 64) {
    int lane = idx & 63;
    int mt   = (idx >> 6) % 14;
    int ks   = idx / (14 * 64);
    int o    = mt * 16 + (lane & 15);
    int tap  = ks >> 1, s = ks & 1;
    int ky   = tap / 5, kx = tap % 5;
    int cb   = s * 32 + (lane >> 4) * 8;
    u32 pk[4];
    #pragma unroll
    for (int p = 0; p < 4; ++p) {
      u16 lo = 0, hi = 0;
      if (o < OE_) {
        lo = f2bf(w_enc[((o * CC_ + cb + 2 * p) * 5 + ky) * 5 + kx]);
        hi = f2bf(w_enc[((o * CC_ + cb + 2 * p + 1) * 5 + ky) * 5 + kx]);
      }
      pk[p] = (u32)lo | ((u32)hi << 16);
    }
    *reinterpret_cast<u32x4*>(wfrag + (size_t)idx * 8) =
        *reinterpret_cast<u32x4*>(pk);
  }
  if (idx < 8 * 4 * 64) {                      // wcf: 2048 chunks
    int lane = idx & 63;
    int mt   = (idx >> 6) & 3;
    int ks   = idx >> 8;
    int o    = mt * 16 + (lane & 15);
    int cb   = ks * 32 + (lane >> 4) * 8;
    u32 pk[4];
    #pragma unroll
    for (int p = 0; p < 4; ++p) {
      u16 lo = f2bf(w_comp[o * C_ + cb + 2 * p]);
      u16 hi = f2bf(w_comp[o * C_ + cb + 2 * p + 1]);
      pk[p] = (u32)lo | ((u32)hi << 16);
    }
    *reinterpret_cast<u32x4*>(wcf + (size_t)idx * 8) =
        *reinterpret_cast<u32x4*>(pk);
  }
  // ---- halo-only zeroing: 1088 wb-rows x 256 16B-chunks ----
  {
    u32x4 z = {0, 0, 0, 0};
    for (int i = idx; i < 1088 * 256; i += 65536) {
      int zi = i >> 8, ck = i & 255;
      int b = zi / 272, r = zi % 272;
      int hp, wb;
      if (r < 30)      { hp = r / 10;             wb = r % 10; }
      else if (r < 80) { hp = 67 + (r - 30) / 10; wb = (r - 30) % 10; }
      else {
        int rr = r - 80;
        hp = 3 + rr / 3;
        int m = rr % 3;
        wb = (m == 0) ? 0 : (m == 1) ? 8 : 9;
      }
      *reinterpret_cast<u32x4*>(
          xw8 + (((size_t)(b * XH_ + hp)) * NWB_ + wb) * (C_ * 8) + ck * 8) = z;
    }
  }
}

// ------------------------------------------------------------------
// Kernel 1: 1x1 compressor via MFMA (unchanged from R24).
// ------------------------------------------------------------------
__global__ __launch_bounds__(256) void compress_k(
    const float* __restrict__ x, const u16* __restrict__ wcf,
    const float* __restrict__ b_comp, u16* __restrict__ comp,
    u16* __restrict__ xw8) {
  __shared__ float xs[C_ * 20];
  int t   = threadIdx.x;
  int gid = blockIdx.x;
  int wq  = gid & 3;
  int bh  = gid >> 2;
  int b = bh >> 6, h = bh & 63;
  int w0 = wq * 16;

  const float* xrow = x + (size_t)b * C_ * H_ * W_ + (size_t)h * W_ + w0;
  for (int i = t; i < 1024; i += 256) {
    int c = i >> 2, q = i & 3;
    f32x4 v = *reinterpret_cast<const f32x4*>(xrow + (size_t)c * H_ * W_ + q * 4);
    *reinterpret_cast<f32x4*>(xs + c * 20 + q * 4) = v;
  }
  __syncthreads();

  int wv   = __builtin_amdgcn_readfirstlane(t >> 6);   // mt 0..3
  int lane = t & 63;
  int w    = lane & 15;          // pixel within 16-w group
  int lg   = lane >> 4;          // 0..3

  bf16x8 af[8];
  #pragma unroll
  for (int ks = 0; ks < 8; ++ks)
    af[ks] = *reinterpret_cast<const bf16x8*>(
        wcf + (((size_t)ks * 4 + wv) * 64 + lane) * 8);

  f32x4 acc = {0.f, 0.f, 0.f, 0.f};
  #pragma unroll
  for (int ks = 0; ks < 8; ++ks) {
    short vv[8];
    #pragma unroll
    for (int j = 0; j < 8; ++j)
      vv[j] = (short)f2bf(xs[(ks * 32 + lg * 8 + j) * 20 + w]);
    bf16x8 bf = (bf16x8){vv[0], vv[1], vv[2], vv[3], vv[4], vv[5], vv[6], vv[7]};
    acc = __builtin_amdgcn_mfma_f32_16x16x32_bf16(af[ks], bf, acc, 0, 0, 0);
  }

  {
    int cc0 = wv * 16 + lg * 4;
    f32x4 bias = *reinterpret_cast<const f32x4*>(b_comp + cc0);
    u32 p0 = (u32)f2bf(acc[0] + bias[0]) | ((u32)f2bf(acc[1] + bias[1]) << 16);
    u32 p1 = (u32)f2bf(acc[2] + bias[2]) | ((u32)f2bf(acc[3] + bias[3]) << 16);
    u32x2 pk = {p0, p1};
    *reinterpret_cast<u32x2*>(comp + ((size_t)bh * 64 + w0 + w) * CC_ + cc0) = pk;
  }

  {
    int ww = t & 15, cq = t >> 4;
    int wp = w0 + ww + 3;
    size_t base = (((size_t)(b * XH_ + h + 3)) * NWB_ + (wp >> 3)) * (C_ * 8) + (wp & 7);
    #pragma unroll
    for (int i = 0; i < 16; ++i) {
      int c = cq * 16 + i;
      xw8[base + c * 8] = f2bf(xs[c * 20 + ww]);
    }
  }
}

// ------------------------------------------------------------------
// Kernel 2: encoder MFMA GEMM v9 (unchanged).
// ------------------------------------------------------------------
#define ELG_ 32256   // 224*36*4

__device__ __forceinline__ void enc_lda(
    bf16x8 (&a)[2], const u16* __restrict__ wfrag,
    int ks, int mtbase, int lane) {
  #pragma unroll
  for (int mm = 0; mm < 2; ++mm)
    a[mm] = *reinterpret_cast<const bf16x8*>(
        wfrag + (((size_t)ks * 14 + mtbase + mm) * 64 + lane) * 8);
}

__device__ __forceinline__ void enc_step(
    int ks, const char* lds, const bf16x8 (&a)[2], f32x4 (&acc)[2][2],
    int nlane, int kq) {
  int tap = ks >> 1, s = ks & 1;
  int ky = tap / 5, kx = tap % 5;   // constants after full unroll
  bf16x8 bf[2];
  #pragma unroll
  for (int nt = 0; nt < 2; ++nt) {
    int col = nt * 16 + nlane + kx;
    int byte = (((ky * 36 + col) * 64 + s * 32 + kq * 8) * 2) ^ ((col & 7) << 4);
    bf[nt] = *reinterpret_cast<const bf16x8*>(lds + byte);
  }
  #pragma unroll
  for (int mm = 0; mm < 2; ++mm)
    #pragma unroll
    for (int nt = 0; nt < 2; ++nt)
      acc[mm][nt] = __builtin_amdgcn_mfma_f32_16x16x32_bf16(
          a[mm], bf[nt], acc[mm][nt], 0, 0, 0);
}

__global__ __launch_bounds__(512) void enc_mfma_k(
    const u16* __restrict__ comp, const u16* __restrict__ wfrag,
    const float* __restrict__ b_enc, u16* __restrict__ smax) {
  __shared__ __align__(16) char lds[ELG_];

  int t   = threadIdx.x;                   // 0..511
  int bid = blockIdx.x;
  int swz = (bid & 7) * 64 + (bid >> 3);   // 512 blocks, bijective
  int wh  = swz & 1;
  int bh  = swz >> 1;
  int b = bh >> 6, h = bh & 63;
  int w0 = wh * 32;

  {
    const u16* cbse = comp + (size_t)b * H_ * W_ * CC_;
    for (int i = t; i < 1440; i += 512) {
      int q = i & 7, colr = i >> 3;
      int col = colr % 36, r = colr / 36;
      int hh = h - 2 + r, gw = w0 - 2 + col;
      u32x4 v = {0, 0, 0, 0};
      if ((unsigned)hh < H_ && (unsigned)gw < W_)
        v = *reinterpret_cast<const u32x4*>(cbse + ((size_t)hh * W_ + gw) * CC_ + q * 8);
      int byte = ((r * 36 + col) * 128 + q * 16) ^ ((col & 7) << 4);
      *reinterpret_cast<u32x4*>(lds + byte) = v;
    }
  }
  __syncthreads();   // B ready; no further barriers in K-loop

  int wv    = __builtin_amdgcn_readfirstlane(t >> 6);   // 0..7
  int lane  = t & 63;
  int nlane = lane & 15, kq = lane >> 4;
  int mtbase = wv * 2;

  f32x4 acc[2][2];
  #pragma unroll
  for (int mm = 0; mm < 2; ++mm)
    #pragma unroll
    for (int nt = 0; nt < 2; ++nt) acc[mm][nt] = (f32x4){0.f, 0.f, 0.f, 0.f};

  if (wv < 7) {
    bf16x8 abuf[4][2];
    #pragma unroll
    for (int p = 0; p < 4; ++p) enc_lda(abuf[p], wfrag, p, mtbase, lane);
    #pragma unroll
    for (int ks = 0; ks < 50; ++ks) {       // fully unrolled, static
      enc_step(ks, lds, abuf[ks & 3], acc, nlane, kq);
      if (ks < 46) enc_lda(abuf[ks & 3], wfrag, ks + 4, mtbase, lane);
    }
  }

  __syncthreads();
  float* lg = (float*)lds;
  if (wv < 7) {
    #pragma unroll
    for (int mm = 0; mm < 2; ++mm) {
      #pragma unroll
      for (int nt = 0; nt < 2; ++nt) {
        #pragma unroll
        for (int r = 0; r < 4; ++r) {
          int m  = (mtbase + mm) * 16 + kq * 4 + r;
          int px = nt * 16 + nlane;
          lg[m * 36 + px] = acc[mm][nt][r] + (m < OE_ ? b_enc[m] : 0.f);
        }
      }
    }
  }
  __syncthreads();

  if (t < 128) {
    int px = t & 31, rr = t >> 5;
    float v[49];
    float mx = -1e30f;
    #pragma unroll
    for (int n = 0; n < 49; ++n) {
      v[n] = lg[(4 * n + rr) * 36 + px];
      mx = fmaxf(mx, v[n]);
    }
    float sum = 0.f;
    #pragma unroll
    for (int n = 0; n < 49; ++n) { v[n] = __expf(v[n] - mx); sum += v[n]; }
    float inv = 1.f / sum;
    u16* so = smax + ((size_t)bh * 64 + w0 + px) * OE_;
    #pragma unroll
    for (int n = 0; n < 49; ++n) so[n * 4 + rr] = f2bf(v[n] * inv);   // [n][r] bf16
  }
}

// ------------------------------------------------------------------
// Kernel 3: CARAFE v23 — depth-4 A prefetch: all 4 mt panels' frags
// (16 b128) issued back-to-back upfront; one exposed latency, the
// rest hides under 3 mt of MFMA+stores.  buf[4][4] statically
// indexed after unroll.  VGPR ~120 target (falsifier: >128 or spill).
// ------------------------------------------------------------------
__device__ __forceinline__ void carafe_lda(
    bf16x8 (&buf)[4], const u16* __restrict__ xb,
    int c, int h, int wb0, int lg) {
  #pragma unroll
  for (int ks = 0; ks < 4; ++ks) {
    int dy = ks * 2 + (lg >> 1);
    buf[ks] = *reinterpret_cast<const bf16x8*>(
        xb + (((size_t)(h + dy)) * NWB_ + wb0 + (lg & 1)) * (C_ * 8) + c * 8);
  }
}

__global__ __launch_bounds__(256) void carafe_k(
    const u16* __restrict__ xw8, const u16* __restrict__ smax,
    float* __restrict__ out) {
  __shared__ __align__(8) u16 svl[16 * 200];   // 6,400 B
  int t   = threadIdx.x;
  int bid = blockIdx.x;                        // 2048 blocks
  int swz = (bid & 7) * 256 + (bid >> 3);      // bijective XCD chunk
  int mh  = swz & 1;           // M half
  int ws2 = (swz >> 1) & 3;    // 16-pixel group
  int h   = (swz >> 3) & 63;
  int b   = swz >> 9;
  int w00 = ws2 * 16;

  for (int idx = t; idx < 784; idx += 256) {
    int pix = idx / 49, n = idx - pix * 49;
    const u16* sp = smax +
        ((size_t)((b * 64 + h) * 64) + w00 + pix) * OE_ + n * 4;
    *reinterpret_cast<u32x2*>(svl + pix * 200 + n * 4) =
        *reinterpret_cast<const u32x2*>(sp);
  }
  __syncthreads();

  int wv   = t >> 6;           // 0..3
  int lane = t & 63;
  int ws   = wv & 1;
  int mq   = wv >> 1;
  int w0   = w00 + ws * 8;
  int wb0  = w0 >> 3;
  const u16* svb = svl + ws * 8 * 200;

  int col = lane & 15;
  int wi  = col >> 1, q = col & 1;
  int lg  = lane >> 4;
  int mrow = lane & 15;

  bf16x8 bfr[2][4];
  #pragma unroll
  for (int p = 0; p < 2; ++p) {
    #pragma unroll
    for (int ks = 0; ks < 4; ++ks) {
      short v[8];
      #pragma unroll
      for (int j = 0; j < 8; ++j) {
        int k   = ks * 32 + lg * 8 + j;
        int dy  = k >> 4, dxp = k & 15;
        int dx  = dxp - wi;
        u16 s = 0;
        if (dy < 7 && dx >= 0 && dx < 7)
          s = svb[wi * 200 + (dy * 7 + dx) * 4 + 2 * p + q];
        v[j] = (short)s;
      }
      bfr[p][ks] = (bf16x8){v[0], v[1], v[2], v[3], v[4], v[5], v[6], v[7]};
    }
  }

  // ---- depth-4 A prefetch: all 16 frags issued back-to-back ----
  const u16* xb = xw8 + (size_t)b * XH_ * NWB_ * (C_ * 8);
  int mt0 = mh * 8 + mq * 4;
  bf16x8 buf[4][4];
  #pragma unroll
  for (int i = 0; i < 4; ++i)
    carafe_lda(buf[i], xb, (mt0 + i) * 16 + mrow, h, wb0, lg);

  #pragma unroll
  for (int i = 0; i < 4; ++i) {
    int mt = mt0 + i;
    f32x4 acc0 = {0.f, 0.f, 0.f, 0.f};
    f32x4 acc1 = {0.f, 0.f, 0.f, 0.f};
    #pragma unroll
    for (int ks = 0; ks < 4; ++ks) {
      acc0 = __builtin_amdgcn_mfma_f32_16x16x32_bf16(buf[i][ks], bfr[0][ks], acc0, 0, 0, 0);
      acc1 = __builtin_amdgcn_mfma_f32_16x16x32_bf16(buf[i][ks], bfr[1][ks], acc1, 0, 0, 0);
    }
    float* o0 = out +
        ((size_t)(b * C_ + mt * 16 + lg * 4) * OH_ + 2 * h) * OW_ + 2 * w0 + col;
    o0[0]                     = acc0[0];
    o0[(size_t)OH_ * OW_]     = acc0[1];
    o0[2 * (size_t)OH_ * OW_] = acc0[2];
    o0[3 * (size_t)OH_ * OW_] = acc0[3];
    float* o1 = o0 + OW_;
    o1[0]                     = acc1[0];
    o1[(size_t)OH_ * OW_]     = acc1[1];
    o1[2 * (size_t)OH_ * OW_] = acc1[2];
    o1[3 * (size_t)OH_ * OW_] = acc1[3];
  }
}

// ------------------------------------------------------------------
extern "C" void kernel_launch(void* const* d_in, const int* in_sizes, int n_in,
                              void* d_out, int out_size, void* d_ws, size_t ws_size,
                              hipStream_t stream) {
  const float* x      = (const float*)d_in[0];
  const float* w_comp = (const float*)d_in[1];
  const float* b_comp = (const float*)d_in[2];
  const float* w_enc  = (const float*)d_in[3];
  const float* b_enc  = (const float*)d_in[4];
  float* out = (float*)d_out;

  u16* smax  = (u16*)d_ws;                      // 3,211,264 bf16
  u16* wfrag = smax + 3211264;                  //   358,400 bf16
  u16* wcf   = wfrag + 358400;                  //    16,384 bf16
  u16* comp  = wcf + 16384;                     // 1,048,576 bf16
  u16* xw8   = comp + 1048576;                  // 5,898,240 bf16 (~21MB total)

  prep_weights<<<256, 256, 0, stream>>>(w_comp, w_enc, wfrag, wcf, xw8);
  compress_k<<<B_ * H_ * 4, 256, 0, stream>>>(x, wcf, b_comp, comp, xw8);
  enc_mfma_k<<<512, 512, 0, stream>>>(comp, wfrag, b_enc, smax);
  carafe_k<<<2048, 256, 0, stream>>>(xw8, smax, out);
}

// Round 26
// 65.684 us; speedup vs baseline: 2.1184x; 1.0452x over previous
//
#include <hip/hip_runtime.h>
#include <math.h>
#include <stdint.h>

#define B_   4
#define C_   256
#define H_   64
#define W_   64
#define CC_  64
#define OE_  196
#define OH_  128
#define OW_  128
#define XH_  72    // padded height
#define NWB_ 10    // 80 padded cols / 8

typedef uint32_t u32;
typedef unsigned short u16;
typedef __attribute__((ext_vector_type(8))) short bf16x8;
typedef __attribute__((ext_vector_type(4))) float f32x4;
typedef __attribute__((ext_vector_type(4))) u32 u32x4;
typedef __attribute__((ext_vector_type(2))) u32 u32x2;

__device__ __forceinline__ u16 f2bf(float f) {
  u32 u = __builtin_bit_cast(u32, f);
  u32 r = (u + 0x7FFFu + ((u >> 16) & 1u)) >> 16;   // RNE
  return (u16)r;
}

// ------------------------------------------------------------------
// Kernel 0: weight re-layouts + HALO-ONLY xw8 zeroing (unchanged).
// ------------------------------------------------------------------
__global__ __launch_bounds__(256) void prep_weights(
    const float* __restrict__ w_comp, const float* __restrict__ w_enc,
    u16* __restrict__ wfrag, u16* __restrict__ wcf,
    u16* __restrict__ xw8) {
  int idx = blockIdx.x * 256 + threadIdx.x;    // 0..65535
  if (idx < 50 * 14 * 64) {
    int lane = idx & 63;
    int mt   = (idx >> 6) % 14;
    int ks   = idx / (14 * 64);
    int o    = mt * 16 + (lane & 15);
    int tap  = ks >> 1, s = ks & 1;
    int ky   = tap / 5, kx = tap % 5;
    int cb   = s * 32 + (lane >> 4) * 8;
    u32 pk[4];
    #pragma unroll
    for (int p = 0; p < 4; ++p) {
      u16 lo = 0, hi = 0;
      if (o < OE_) {
        lo = f2bf(w_enc[((o * CC_ + cb + 2 * p) * 5 + ky) * 5 + kx]);
        hi = f2bf(w_enc[((o * CC_ + cb + 2 * p + 1) * 5 + ky) * 5 + kx]);
      }
      pk[p] = (u32)lo | ((u32)hi << 16);
    }
    *reinterpret_cast<u32x4*>(wfrag + (size_t)idx * 8) =
        *reinterpret_cast<u32x4*>(pk);
  }
  if (idx < 8 * 4 * 64) {                      // wcf: 2048 chunks
    int lane = idx & 63;
    int mt   = (idx >> 6) & 3;
    int ks   = idx >> 8;
    int o    = mt * 16 + (lane & 15);
    int cb   = ks * 32 + (lane >> 4) * 8;
    u32 pk[4];
    #pragma unroll
    for (int p = 0; p < 4; ++p) {
      u16 lo = f2bf(w_comp[o * C_ + cb + 2 * p]);
      u16 hi = f2bf(w_comp[o * C_ + cb + 2 * p + 1]);
      pk[p] = (u32)lo | ((u32)hi << 16);
    }
    *reinterpret_cast<u32x4*>(wcf + (size_t)idx * 8) =
        *reinterpret_cast<u32x4*>(pk);
  }
  // ---- halo-only zeroing ----
  {
    u32x4 z = {0, 0, 0, 0};
    for (int i = idx; i < 1088 * 256; i += 65536) {
      int zi = i >> 8, ck = i & 255;
      int b = zi / 272, r = zi % 272;
      int hp, wb;
      if (r < 30)      { hp = r / 10;             wb = r % 10; }
      else if (r < 80) { hp = 67 + (r - 30) / 10; wb = (r - 30) % 10; }
      else {
        int rr = r - 80;
        hp = 3 + rr / 3;
        int m = rr % 3;
        wb = (m == 0) ? 0 : (m == 1) ? 8 : 9;
      }
      *reinterpret_cast<u32x4*>(
          xw8 + (((size_t)(b * XH_ + hp)) * NWB_ + wb) * (C_ * 8) + ck * 8) = z;
    }
  }
}

// ------------------------------------------------------------------
// Kernel 1: 1x1 compressor via MFMA (unchanged from R24).
// ------------------------------------------------------------------
__global__ __launch_bounds__(256) void compress_k(
    const float* __restrict__ x, const u16* __restrict__ wcf,
    const float* __restrict__ b_comp, u16* __restrict__ comp,
    u16* __restrict__ xw8) {
  __shared__ float xs[C_ * 20];
  int t   = threadIdx.x;
  int gid = blockIdx.x;
  int wq  = gid & 3;
  int bh  = gid >> 2;
  int b = bh >> 6, h = bh & 63;
  int w0 = wq * 16;

  const float* xrow = x + (size_t)b * C_ * H_ * W_ + (size_t)h * W_ + w0;
  for (int i = t; i < 1024; i += 256) {
    int c = i >> 2, q = i & 3;
    f32x4 v = *reinterpret_cast<const f32x4*>(xrow + (size_t)c * H_ * W_ + q * 4);
    *reinterpret_cast<f32x4*>(xs + c * 20 + q * 4) = v;
  }
  __syncthreads();

  int wv   = __builtin_amdgcn_readfirstlane(t >> 6);   // mt 0..3
  int lane = t & 63;
  int w    = lane & 15;
  int lg   = lane >> 4;

  bf16x8 af[8];
  #pragma unroll
  for (int ks = 0; ks < 8; ++ks)
    af[ks] = *reinterpret_cast<const bf16x8*>(
        wcf + (((size_t)ks * 4 + wv) * 64 + lane) * 8);

  f32x4 acc = {0.f, 0.f, 0.f, 0.f};
  #pragma unroll
  for (int ks = 0; ks < 8; ++ks) {
    short vv[8];
    #pragma unroll
    for (int j = 0; j < 8; ++j)
      vv[j] = (short)f2bf(xs[(ks * 32 + lg * 8 + j) * 20 + w]);
    bf16x8 bf = (bf16x8){vv[0], vv[1], vv[2], vv[3], vv[4], vv[5], vv[6], vv[7]};
    acc = __builtin_amdgcn_mfma_f32_16x16x32_bf16(af[ks], bf, acc, 0, 0, 0);
  }

  {
    int cc0 = wv * 16 + lg * 4;
    f32x4 bias = *reinterpret_cast<const f32x4*>(b_comp + cc0);
    u32 p0 = (u32)f2bf(acc[0] + bias[0]) | ((u32)f2bf(acc[1] + bias[1]) << 16);
    u32 p1 = (u32)f2bf(acc[2] + bias[2]) | ((u32)f2bf(acc[3] + bias[3]) << 16);
    u32x2 pk = {p0, p1};
    *reinterpret_cast<u32x2*>(comp + ((size_t)bh * 64 + w0 + w) * CC_ + cc0) = pk;
  }

  {
    int ww = t & 15, cq = t >> 4;
    int wp = w0 + ww + 3;
    size_t base = (((size_t)(b * XH_ + h + 3)) * NWB_ + (wp >> 3)) * (C_ * 8) + (wp & 7);
    #pragma unroll
    for (int i = 0; i < 16; ++i) {
      int c = cq * 16 + i;
      xw8[base + c * 8] = f2bf(xs[c * 20 + ww]);
    }
  }
}

// ------------------------------------------------------------------
// Kernel 2: encoder MFMA GEMM v10 — same K-loop; epilogue now writes
// the banded B-matrix for carafe DIRECTLY in MFMA fragment layout
// (bfrB[b][h][wg][p][ks][lane][j] bf16; every element written, zeros
// included).  Runtime-indexed v[] bounced through a 12.5KB LDS row.
// ------------------------------------------------------------------
#define ELG_ 32256   // 224*36*4

__device__ __forceinline__ void enc_lda(
    bf16x8 (&a)[2], const u16* __restrict__ wfrag,
    int ks, int mtbase, int lane) {
  #pragma unroll
  for (int mm = 0; mm < 2; ++mm)
    a[mm] = *reinterpret_cast<const bf16x8*>(
        wfrag + (((size_t)ks * 14 + mtbase + mm) * 64 + lane) * 8);
}

__device__ __forceinline__ void enc_step(
    int ks, const char* lds, const bf16x8 (&a)[2], f32x4 (&acc)[2][2],
    int nlane, int kq) {
  int tap = ks >> 1, s = ks & 1;
  int ky = tap / 5, kx = tap % 5;
  bf16x8 bf[2];
  #pragma unroll
  for (int nt = 0; nt < 2; ++nt) {
    int col = nt * 16 + nlane + kx;
    int byte = (((ky * 36 + col) * 64 + s * 32 + kq * 8) * 2) ^ ((col & 7) << 4);
    bf[nt] = *reinterpret_cast<const bf16x8*>(lds + byte);
  }
  #pragma unroll
  for (int mm = 0; mm < 2; ++mm)
    #pragma unroll
    for (int nt = 0; nt < 2; ++nt)
      acc[mm][nt] = __builtin_amdgcn_mfma_f32_16x16x32_bf16(
          a[mm], bf[nt], acc[mm][nt], 0, 0, 0);
}

__global__ __launch_bounds__(512) void enc_mfma_k(
    const u16* __restrict__ comp, const u16* __restrict__ wfrag,
    const float* __restrict__ b_enc, u16* __restrict__ bfrB) {
  __shared__ __align__(16) char lds[ELG_];

  int t   = threadIdx.x;                   // 0..511
  int bid = blockIdx.x;
  int swz = (bid & 7) * 64 + (bid >> 3);   // 512 blocks, bijective
  int wh  = swz & 1;
  int bh  = swz >> 1;
  int b = bh >> 6, h = bh & 63;
  int w0 = wh * 32;

  {
    const u16* cbse = comp + (size_t)b * H_ * W_ * CC_;
    for (int i = t; i < 1440; i += 512) {
      int q = i & 7, colr = i >> 3;
      int col = colr % 36, r = colr / 36;
      int hh = h - 2 + r, gw = w0 - 2 + col;
      u32x4 v = {0, 0, 0, 0};
      if ((unsigned)hh < H_ && (unsigned)gw < W_)
        v = *reinterpret_cast<const u32x4*>(cbse + ((size_t)hh * W_ + gw) * CC_ + q * 8);
      int byte = ((r * 36 + col) * 128 + q * 16) ^ ((col & 7) << 4);
      *reinterpret_cast<u32x4*>(lds + byte) = v;
    }
  }
  __syncthreads();

  int wv    = __builtin_amdgcn_readfirstlane(t >> 6);   // 0..7
  int lane  = t & 63;
  int nlane = lane & 15, kq = lane >> 4;
  int mtbase = wv * 2;

  f32x4 acc[2][2];
  #pragma unroll
  for (int mm = 0; mm < 2; ++mm)
    #pragma unroll
    for (int nt = 0; nt < 2; ++nt) acc[mm][nt] = (f32x4){0.f, 0.f, 0.f, 0.f};

  if (wv < 7) {
    bf16x8 abuf[4][2];
    #pragma unroll
    for (int p = 0; p < 4; ++p) enc_lda(abuf[p], wfrag, p, mtbase, lane);
    #pragma unroll
    for (int ks = 0; ks < 50; ++ks) {
      enc_step(ks, lds, abuf[ks & 3], acc, nlane, kq);
      if (ks < 46) enc_lda(abuf[ks & 3], wfrag, ks + 4, mtbase, lane);
    }
  }

  __syncthreads();
  float* lg = (float*)lds;
  if (wv < 7) {
    #pragma unroll
    for (int mm = 0; mm < 2; ++mm) {
      #pragma unroll
      for (int nt = 0; nt < 2; ++nt) {
        #pragma unroll
        for (int r = 0; r < 4; ++r) {
          int m  = (mtbase + mm) * 16 + kq * 4 + r;
          int px = nt * 16 + nlane;
          lg[m * 36 + px] = acc[mm][nt][r] + (m < OE_ ? b_enc[m] : 0.f);
        }
      }
    }
  }
  __syncthreads();

  // ---- softmax (registers) ----
  float v[49];
  float inv = 0.f;
  if (t < 128) {
    int px = t & 31, rr = t >> 5;
    float mx = -1e30f;
    #pragma unroll
    for (int n = 0; n < 49; ++n) {
      v[n] = lg[(4 * n + rr) * 36 + px];
      mx = fmaxf(mx, v[n]);
    }
    float sum = 0.f;
    #pragma unroll
    for (int n = 0; n < 49; ++n) { v[n] = __expf(v[n] - mx); sum += v[n]; }
    inv = 1.f / sum;
  }
  __syncthreads();   // all lg reads done; lds reusable

  // ---- banded-B write in fragment layout ----
  if (t < 128) {
    int px = t & 31, rr = t >> 5;
    u16* sva = (u16*)lds;
    int myo = (px * 4 + rr) * 49;
    #pragma unroll
    for (int n = 0; n < 49; ++n) sva[myo + n] = f2bf(v[n] * inv);

    int wi = px & 7, wg = wh * 4 + (px >> 3);
    int p = rr >> 1, q = rr & 1;
    size_t bb = ((((size_t)(b * 64 + h) * 8 + wg) * 2 + p) * 4) * 512 +
                (size_t)(wi * 2 + q) * 8;
    #pragma unroll
    for (int ks = 0; ks < 4; ++ks) {
      #pragma unroll
      for (int lg2 = 0; lg2 < 4; ++lg2) {
        u32 pk[4];
        #pragma unroll
        for (int jp = 0; jp < 4; ++jp) {
          u16 e[2];
          #pragma unroll
          for (int u = 0; u < 2; ++u) {
            int j  = jp * 2 + u;
            int k  = ks * 32 + lg2 * 8 + j;
            int dy = k >> 4, dxp = k & 15;
            int dx = dxp - wi;
            bool ok = (dy < 7) && (dx >= 0) && (dx < 7);
            int idx = ok ? (dy * 7 + dx) : 0;
            u16 s = sva[myo + idx];
            e[u] = ok ? s : (u16)0;
          }
          pk[jp] = (u32)e[0] | ((u32)e[1] << 16);
        }
        *reinterpret_cast<u32x4*>(bfrB + bb + (size_t)ks * 512 + lg2 * 128) =
            *reinterpret_cast<u32x4*>(pk);
      }
    }
  }
}

// ------------------------------------------------------------------
// Kernel 3: CARAFE v24 — zero-LDS, zero-barrier: 8 coalesced B-frag
// b128 loads (precomputed by enc) + A ping-pong + 32 MFMA + stores.
// ------------------------------------------------------------------
__device__ __forceinline__ void carafe_lda(
    bf16x8 (&buf)[4], const u16* __restrict__ xb,
    int c, int h, int wg, int lg) {
  #pragma unroll
  for (int ks = 0; ks < 4; ++ks) {
    int dy = ks * 2 + (lg >> 1);
    buf[ks] = *reinterpret_cast<const bf16x8*>(
        xb + (((size_t)(h + dy)) * NWB_ + wg + (lg & 1)) * (C_ * 8) + c * 8);
  }
}

__global__ __launch_bounds__(256) void carafe_k(
    const u16* __restrict__ xw8, const u16* __restrict__ bfrB,
    float* __restrict__ out) {
  int t   = threadIdx.x;
  int bid = blockIdx.x;                        // 2048 blocks
  int swz = (bid & 7) * 256 + (bid >> 3);      // bijective XCD chunk
  int mh  = swz & 1;
  int wgp = (swz >> 1) & 3;
  int h   = (swz >> 3) & 63;
  int b   = swz >> 9;

  int wv   = t >> 6;
  int lane = t & 63;
  int wg   = wgp * 2 + (wv & 1);
  int mq   = wv >> 1;
  int mt0  = mh * 8 + mq * 4;
  int col  = lane & 15;
  int lg   = lane >> 4;
  int mrow = lane & 15;
  int w0   = wg * 8;

  // ---- B fragments: 8 coalesced b128 loads ----
  bf16x8 bfp[2][4];
  size_t bbase = (((size_t)(b * 64 + h) * 8 + wg) * 2) * 4 * 512;
  #pragma unroll
  for (int p = 0; p < 2; ++p)
    #pragma unroll
    for (int ks = 0; ks < 4; ++ks)
      bfp[p][ks] = *reinterpret_cast<const bf16x8*>(
          bfrB + bbase + (size_t)(p * 4 + ks) * 512 + lane * 8);

  // ---- A ping-pong over 4 M-tiles ----
  const u16* xb = xw8 + (size_t)b * XH_ * NWB_ * (C_ * 8);
  bf16x8 bufA[4], bufB[4];
  carafe_lda(bufA, xb, mt0 * 16 + mrow, h, wg, lg);

  #pragma unroll
  for (int i = 0; i < 4; ++i) {
    int mt = mt0 + i;
    if (i < 3) {
      if (i & 1) carafe_lda(bufA, xb, (mt + 1) * 16 + mrow, h, wg, lg);
      else       carafe_lda(bufB, xb, (mt + 1) * 16 + mrow, h, wg, lg);
    }
    f32x4 acc0 = {0.f, 0.f, 0.f, 0.f};
    f32x4 acc1 = {0.f, 0.f, 0.f, 0.f};
    #pragma unroll
    for (int ks = 0; ks < 4; ++ks) {
      bf16x8 af = (i & 1) ? bufB[ks] : bufA[ks];
      acc0 = __builtin_amdgcn_mfma_f32_16x16x32_bf16(af, bfp[0][ks], acc0, 0, 0, 0);
      acc1 = __builtin_amdgcn_mfma_f32_16x16x32_bf16(af, bfp[1][ks], acc1, 0, 0, 0);
    }
    float* o0 = out +
        ((size_t)(b * C_ + mt * 16 + lg * 4) * OH_ + 2 * h) * OW_ + 2 * w0 + col;
    o0[0]                     = acc0[0];
    o0[(size_t)OH_ * OW_]     = acc0[1];
    o0[2 * (size_t)OH_ * OW_] = acc0[2];
    o0[3 * (size_t)OH_ * OW_] = acc0[3];
    float* o1 = o0 + OW_;
    o1[0]                     = acc1[0];
    o1[(size_t)OH_ * OW_]     = acc1[1];
    o1[2 * (size_t)OH_ * OW_] = acc1[2];
    o1[3 * (size_t)OH_ * OW_] = acc1[3];
  }
}

// ------------------------------------------------------------------
extern "C" void kernel_launch(void* const* d_in, const int* in_sizes, int n_in,
                              void* d_out, int out_size, void* d_ws, size_t ws_size,
                              hipStream_t stream) {
  const float* x      = (const float*)d_in[0];
  const float* w_comp = (const float*)d_in[1];
  const float* b_comp = (const float*)d_in[2];
  const float* w_enc  = (const float*)d_in[3];
  const float* b_enc  = (const float*)d_in[4];
  float* out = (float*)d_out;

  u16* bfrB  = (u16*)d_ws;                      // 8,388,608 bf16 (16MB)
  u16* wfrag = bfrB + 8388608;                  //   358,400 bf16
  u16* wcf   = wfrag + 358400;                  //    16,384 bf16
  u16* comp  = wcf + 16384;                     // 1,048,576 bf16
  u16* xw8   = comp + 1048576;                  // 5,898,240 bf16 (~31MB total)

  prep_weights<<<256, 256, 0, stream>>>(w_comp, w_enc, wfrag, wcf, xw8);
  compress_k<<<B_ * H_ * 4, 256, 0, stream>>>(x, wcf, b_comp, comp, xw8);
  enc_mfma_k<<<512, 512, 0, stream>>>(comp, wfrag, b_enc, bfrB);
  carafe_k<<<2048, 256, 0, stream>>>(xw8, bfrB, out);
}

// Round 27
// 64.023 us; speedup vs baseline: 2.1733x; 1.0259x over previous
//
#include <hip/hip_runtime.h>
#include <math.h>
#include <stdint.h>

#define B_   4
#define C_   256
#define H_   64
#define W_   64
#define CC_  64
#define OE_  196
#define OH_  128
#define OW_  128
#define XH_  72    // padded height
#define NWB_ 10    // 80 padded cols / 8

typedef uint32_t u32;
typedef unsigned short u16;
typedef __attribute__((ext_vector_type(8))) short bf16x8;
typedef __attribute__((ext_vector_type(4))) float f32x4;
typedef __attribute__((ext_vector_type(4))) u32 u32x4;
typedef __attribute__((ext_vector_type(2))) u32 u32x2;

__device__ __forceinline__ u16 f2bf(float f) {
  u32 u = __builtin_bit_cast(u32, f);
  u32 r = (u + 0x7FFFu + ((u >> 16) & 1u)) >> 16;   // RNE
  return (u16)r;
}

// ------------------------------------------------------------------
// Kernel 0: weight re-layouts + h-halo-only xw8 zeroing (w-halo is
// now written by compress itself; rows {0,1,2,67..71} x all wb).
// ------------------------------------------------------------------
__global__ __launch_bounds__(256) void prep_weights(
    const float* __restrict__ w_comp, const float* __restrict__ w_enc,
    u16* __restrict__ wfrag, u16* __restrict__ wcf,
    u16* __restrict__ xw8) {
  int idx = blockIdx.x * 256 + threadIdx.x;    // 0..65535
  if (idx < 50 * 14 * 64) {
    int lane = idx & 63;
    int mt   = (idx >> 6) % 14;
    int ks   = idx / (14 * 64);
    int o    = mt * 16 + (lane & 15);
    int tap  = ks >> 1, s = ks & 1;
    int ky   = tap / 5, kx = tap % 5;
    int cb   = s * 32 + (lane >> 4) * 8;
    u32 pk[4];
    #pragma unroll
    for (int p = 0; p < 4; ++p) {
      u16 lo = 0, hi = 0;
      if (o < OE_) {
        lo = f2bf(w_enc[((o * CC_ + cb + 2 * p) * 5 + ky) * 5 + kx]);
        hi = f2bf(w_enc[((o * CC_ + cb + 2 * p + 1) * 5 + ky) * 5 + kx]);
      }
      pk[p] = (u32)lo | ((u32)hi << 16);
    }
    *reinterpret_cast<u32x4*>(wfrag + (size_t)idx * 8) =
        *reinterpret_cast<u32x4*>(pk);
  }
  if (idx < 8 * 4 * 64) {                      // wcf: 2048 chunks
    int lane = idx & 63;
    int mt   = (idx >> 6) & 3;
    int ks   = idx >> 8;
    int o    = mt * 16 + (lane & 15);
    int cb   = ks * 32 + (lane >> 4) * 8;
    u32 pk[4];
    #pragma unroll
    for (int p = 0; p < 4; ++p) {
      u16 lo = f2bf(w_comp[o * C_ + cb + 2 * p]);
      u16 hi = f2bf(w_comp[o * C_ + cb + 2 * p + 1]);
      pk[p] = (u32)lo | ((u32)hi << 16);
    }
    *reinterpret_cast<u32x4*>(wcf + (size_t)idx * 8) =
        *reinterpret_cast<u32x4*>(pk);
  }
  // ---- h-halo zeroing: 4b x 8rows x 10wb x 256 chunks = 81920 ----
  {
    u32x4 z = {0, 0, 0, 0};
    for (int i = idx; i < 81920; i += 65536) {
      int ck = i & 255, zi = i >> 8;        // zi 0..319
      int b = zi / 80, r = zi % 80;
      int hp8 = r / 10, wb = r % 10;
      int hp = (hp8 < 3) ? hp8 : 64 + hp8;  // 0,1,2,67..71
      *reinterpret_cast<u32x4*>(
          xw8 + (((size_t)(b * XH_ + hp)) * NWB_ + wb) * (C_ * 8) + ck * 8) = z;
    }
  }
}

// ------------------------------------------------------------------
// Kernel 1: 1x1 compressor via MFMA, wb-ALIGNED blocks.
// Block (b,h,wq), wq 0..4: covers padded cols wp = wq*16..wq*16+15
// (pixels w = wq*16-3..+12; OOB pixels stage as 0 -> w-halo written
// free).  xs[256][25] (stride-25: conflict-free gather + B-build).
// xw8 write: thread=c gathers 8 pixels -> 2 coalesced b128 stores
// (was 16 scalar stores).  comp stores bounds-checked.
// ------------------------------------------------------------------
__global__ __launch_bounds__(256) void compress_k(
    const float* __restrict__ x, const u16* __restrict__ wcf,
    const float* __restrict__ b_comp, u16* __restrict__ comp,
    u16* __restrict__ xw8) {
  __shared__ float xs[C_ * 25];   // 25,600 B
  int t   = threadIdx.x;
  int gid = blockIdx.x;           // bh*5 + wq
  int wq  = gid % 5;
  int bh  = gid / 5;
  int b = bh >> 6, h = bh & 63;
  int wbase = wq * 16 - 4;        // aligned staging start

  // ---- stage: 256 ch x 5 aligned f32x4 (cols wbase..wbase+19) ----
  const float* xrow = x + (size_t)b * C_ * H_ * W_ + (size_t)h * W_;
  for (int i = t; i < 1280; i += 256) {
    int c = i / 5, q = i - (i / 5) * 5;
    int gw0 = wbase + q * 4;
    f32x4 v = {0.f, 0.f, 0.f, 0.f};
    if ((unsigned)gw0 < 61u)
      v = *reinterpret_cast<const f32x4*>(xrow + (size_t)c * H_ * W_ + gw0);
    float* r = xs + c * 25 + q * 4;
    r[0] = v[0]; r[1] = v[1]; r[2] = v[2]; r[3] = v[3];
  }
  __syncthreads();

  int wv   = __builtin_amdgcn_readfirstlane(t >> 6);   // mt 0..3
  int lane = t & 63;
  int i16  = lane & 15;          // pixel index within block
  int lg   = lane >> 4;          // 0..3

  bf16x8 af[8];
  #pragma unroll
  for (int ks = 0; ks < 8; ++ks)
    af[ks] = *reinterpret_cast<const bf16x8*>(
        wcf + (((size_t)ks * 4 + wv) * 64 + lane) * 8);

  f32x4 acc = {0.f, 0.f, 0.f, 0.f};
  #pragma unroll
  for (int ks = 0; ks < 8; ++ks) {
    short vv[8];
    #pragma unroll
    for (int j = 0; j < 8; ++j)
      vv[j] = (short)f2bf(xs[(ks * 32 + lg * 8 + j) * 25 + i16 + 1]);
    bf16x8 bf = (bf16x8){vv[0], vv[1], vv[2], vv[3], vv[4], vv[5], vv[6], vv[7]};
    acc = __builtin_amdgcn_mfma_f32_16x16x32_bf16(af[ks], bf, acc, 0, 0, 0);
  }

  // ---- comp store (bounds-checked: 13/16/16/16/3 valid) ----
  {
    int w = wq * 16 - 3 + i16;
    if ((unsigned)w < (unsigned)W_) {
      int cc0 = wv * 16 + lg * 4;
      f32x4 bias = *reinterpret_cast<const f32x4*>(b_comp + cc0);
      u32 p0 = (u32)f2bf(acc[0] + bias[0]) | ((u32)f2bf(acc[1] + bias[1]) << 16);
      u32 p1 = (u32)f2bf(acc[2] + bias[2]) | ((u32)f2bf(acc[3] + bias[3]) << 16);
      u32x2 pk = {p0, p1};
      *reinterpret_cast<u32x2*>(comp + ((size_t)bh * 64 + w) * CC_ + cc0) = pk;
    }
  }

  // ---- xw8: thread = channel c; 2 coalesced b128 stores ----
  {
    int c = t;
    size_t row = ((size_t)(b * XH_ + h + 3)) * NWB_;
    #pragma unroll
    for (int g = 0; g < 2; ++g) {
      int wb = wq * 2 + g;
      u32 pk[4];
      #pragma unroll
      for (int jp = 0; jp < 4; ++jp) {
        u16 lo = f2bf(xs[c * 25 + g * 8 + 1 + 2 * jp]);
        u16 hi = f2bf(xs[c * 25 + g * 8 + 2 + 2 * jp]);
        pk[jp] = (u32)lo | ((u32)hi << 16);
      }
      *reinterpret_cast<u32x4*>(xw8 + (row + wb) * (C_ * 8) + c * 8) =
          *reinterpret_cast<u32x4*>(pk);
    }
  }
}

// ------------------------------------------------------------------
// Kernel 2: encoder MFMA GEMM v10 (unchanged from R26): K-loop +
// fused softmax + banded-B fragment write.
// ------------------------------------------------------------------
#define ELG_ 32256   // 224*36*4

__device__ __forceinline__ void enc_lda(
    bf16x8 (&a)[2], const u16* __restrict__ wfrag,
    int ks, int mtbase, int lane) {
  #pragma unroll
  for (int mm = 0; mm < 2; ++mm)
    a[mm] = *reinterpret_cast<const bf16x8*>(
        wfrag + (((size_t)ks * 14 + mtbase + mm) * 64 + lane) * 8);
}

__device__ __forceinline__ void enc_step(
    int ks, const char* lds, const bf16x8 (&a)[2], f32x4 (&acc)[2][2],
    int nlane, int kq) {
  int tap = ks >> 1, s = ks & 1;
  int ky = tap / 5, kx = tap % 5;
  bf16x8 bf[2];
  #pragma unroll
  for (int nt = 0; nt < 2; ++nt) {
    int col = nt * 16 + nlane + kx;
    int byte = (((ky * 36 + col) * 64 + s * 32 + kq * 8) * 2) ^ ((col & 7) << 4);
    bf[nt] = *reinterpret_cast<const bf16x8*>(lds + byte);
  }
  #pragma unroll
  for (int mm = 0; mm < 2; ++mm)
    #pragma unroll
    for (int nt = 0; nt < 2; ++nt)
      acc[mm][nt] = __builtin_amdgcn_mfma_f32_16x16x32_bf16(
          a[mm], bf[nt], acc[mm][nt], 0, 0, 0);
}

__global__ __launch_bounds__(512) void enc_mfma_k(
    const u16* __restrict__ comp, const u16* __restrict__ wfrag,
    const float* __restrict__ b_enc, u16* __restrict__ bfrB) {
  __shared__ __align__(16) char lds[ELG_];

  int t   = threadIdx.x;                   // 0..511
  int bid = blockIdx.x;
  int swz = (bid & 7) * 64 + (bid >> 3);   // 512 blocks, bijective
  int wh  = swz & 1;
  int bh  = swz >> 1;
  int b = bh >> 6, h = bh & 63;
  int w0 = wh * 32;

  {
    const u16* cbse = comp + (size_t)b * H_ * W_ * CC_;
    for (int i = t; i < 1440; i += 512) {
      int q = i & 7, colr = i >> 3;
      int col = colr % 36, r = colr / 36;
      int hh = h - 2 + r, gw = w0 - 2 + col;
      u32x4 v = {0, 0, 0, 0};
      if ((unsigned)hh < H_ && (unsigned)gw < W_)
        v = *reinterpret_cast<const u32x4*>(cbse + ((size_t)hh * W_ + gw) * CC_ + q * 8);
      int byte = ((r * 36 + col) * 128 + q * 16) ^ ((col & 7) << 4);
      *reinterpret_cast<u32x4*>(lds + byte) = v;
    }
  }
  __syncthreads();

  int wv    = __builtin_amdgcn_readfirstlane(t >> 6);   // 0..7
  int lane  = t & 63;
  int nlane = lane & 15, kq = lane >> 4;
  int mtbase = wv * 2;

  f32x4 acc[2][2];
  #pragma unroll
  for (int mm = 0; mm < 2; ++mm)
    #pragma unroll
    for (int nt = 0; nt < 2; ++nt) acc[mm][nt] = (f32x4){0.f, 0.f, 0.f, 0.f};

  if (wv < 7) {
    bf16x8 abuf[4][2];
    #pragma unroll
    for (int p = 0; p < 4; ++p) enc_lda(abuf[p], wfrag, p, mtbase, lane);
    #pragma unroll
    for (int ks = 0; ks < 50; ++ks) {
      enc_step(ks, lds, abuf[ks & 3], acc, nlane, kq);
      if (ks < 46) enc_lda(abuf[ks & 3], wfrag, ks + 4, mtbase, lane);
    }
  }

  __syncthreads();
  float* lg = (float*)lds;
  if (wv < 7) {
    #pragma unroll
    for (int mm = 0; mm < 2; ++mm) {
      #pragma unroll
      for (int nt = 0; nt < 2; ++nt) {
        #pragma unroll
        for (int r = 0; r < 4; ++r) {
          int m  = (mtbase + mm) * 16 + kq * 4 + r;
          int px = nt * 16 + nlane;
          lg[m * 36 + px] = acc[mm][nt][r] + (m < OE_ ? b_enc[m] : 0.f);
        }
      }
    }
  }
  __syncthreads();

  float v[49];
  float inv = 0.f;
  if (t < 128) {
    int px = t & 31, rr = t >> 5;
    float mx = -1e30f;
    #pragma unroll
    for (int n = 0; n < 49; ++n) {
      v[n] = lg[(4 * n + rr) * 36 + px];
      mx = fmaxf(mx, v[n]);
    }
    float sum = 0.f;
    #pragma unroll
    for (int n = 0; n < 49; ++n) { v[n] = __expf(v[n] - mx); sum += v[n]; }
    inv = 1.f / sum;
  }
  __syncthreads();

  if (t < 128) {
    int px = t & 31, rr = t >> 5;
    u16* sva = (u16*)lds;
    int myo = (px * 4 + rr) * 49;
    #pragma unroll
    for (int n = 0; n < 49; ++n) sva[myo + n] = f2bf(v[n] * inv);

    int wi = px & 7, wg = wh * 4 + (px >> 3);
    int p = rr >> 1, q = rr & 1;
    size_t bb = ((((size_t)(b * 64 + h) * 8 + wg) * 2 + p) * 4) * 512 +
                (size_t)(wi * 2 + q) * 8;
    #pragma unroll
    for (int ks = 0; ks < 4; ++ks) {
      #pragma unroll
      for (int lg2 = 0; lg2 < 4; ++lg2) {
        u32 pk[4];
        #pragma unroll
        for (int jp = 0; jp < 4; ++jp) {
          u16 e[2];
          #pragma unroll
          for (int u = 0; u < 2; ++u) {
            int j  = jp * 2 + u;
            int k  = ks * 32 + lg2 * 8 + j;
            int dy = k >> 4, dxp = k & 15;
            int dx = dxp - wi;
            bool ok = (dy < 7) && (dx >= 0) && (dx < 7);
            int idx = ok ? (dy * 7 + dx) : 0;
            u16 s = sva[myo + idx];
            e[u] = ok ? s : (u16)0;
          }
          pk[jp] = (u32)e[0] | ((u32)e[1] << 16);
        }
        *reinterpret_cast<u32x4*>(bfrB + bb + (size_t)ks * 512 + lg2 * 128) =
            *reinterpret_cast<u32x4*>(pk);
      }
    }
  }
}

// ------------------------------------------------------------------
// Kernel 3: CARAFE v24 (unchanged from R26): zero-LDS, zero-barrier.
// ------------------------------------------------------------------
__device__ __forceinline__ void carafe_lda(
    bf16x8 (&buf)[4], const u16* __restrict__ xb,
    int c, int h, int wg, int lg) {
  #pragma unroll
  for (int ks = 0; ks < 4; ++ks) {
    int dy = ks * 2 + (lg >> 1);
    buf[ks] = *reinterpret_cast<const bf16x8*>(
        xb + (((size_t)(h + dy)) * NWB_ + wg + (lg & 1)) * (C_ * 8) + c * 8);
  }
}

__global__ __launch_bounds__(256) void carafe_k(
    const u16* __restrict__ xw8, const u16* __restrict__ bfrB,
    float* __restrict__ out) {
  int t   = threadIdx.x;
  int bid = blockIdx.x;                        // 2048 blocks
  int swz = (bid & 7) * 256 + (bid >> 3);      // bijective XCD chunk
  int mh  = swz & 1;
  int wgp = (swz >> 1) & 3;
  int h   = (swz >> 3) & 63;
  int b   = swz >> 9;

  int wv   = t >> 6;
  int lane = t & 63;
  int wg   = wgp * 2 + (wv & 1);
  int mq   = wv >> 1;
  int mt0  = mh * 8 + mq * 4;
  int col  = lane & 15;
  int lg   = lane >> 4;
  int mrow = lane & 15;
  int w0   = wg * 8;

  bf16x8 bfp[2][4];
  size_t bbase = (((size_t)(b * 64 + h) * 8 + wg) * 2) * 4 * 512;
  #pragma unroll
  for (int p = 0; p < 2; ++p)
    #pragma unroll
    for (int ks = 0; ks < 4; ++ks)
      bfp[p][ks] = *reinterpret_cast<const bf16x8*>(
          bfrB + bbase + (size_t)(p * 4 + ks) * 512 + lane * 8);

  const u16* xb = xw8 + (size_t)b * XH_ * NWB_ * (C_ * 8);
  bf16x8 bufA[4], bufB[4];
  carafe_lda(bufA, xb, mt0 * 16 + mrow, h, wg, lg);

  #pragma unroll
  for (int i = 0; i < 4; ++i) {
    int mt = mt0 + i;
    if (i < 3) {
      if (i & 1) carafe_lda(bufA, xb, (mt + 1) * 16 + mrow, h, wg, lg);
      else       carafe_lda(bufB, xb, (mt + 1) * 16 + mrow, h, wg, lg);
    }
    f32x4 acc0 = {0.f, 0.f, 0.f, 0.f};
    f32x4 acc1 = {0.f, 0.f, 0.f, 0.f};
    #pragma unroll
    for (int ks = 0; ks < 4; ++ks) {
      bf16x8 af = (i & 1) ? bufB[ks] : bufA[ks];
      acc0 = __builtin_amdgcn_mfma_f32_16x16x32_bf16(af, bfp[0][ks], acc0, 0, 0, 0);
      acc1 = __builtin_amdgcn_mfma_f32_16x16x32_bf16(af, bfp[1][ks], acc1, 0, 0, 0);
    }
    float* o0 = out +
        ((size_t)(b * C_ + mt * 16 + lg * 4) * OH_ + 2 * h) * OW_ + 2 * w0 + col;
    o0[0]                     = acc0[0];
    o0[(size_t)OH_ * OW_]     = acc0[1];
    o0[2 * (size_t)OH_ * OW_] = acc0[2];
    o0[3 * (size_t)OH_ * OW_] = acc0[3];
    float* o1 = o0 + OW_;
    o1[0]                     = acc1[0];
    o1[(size_t)OH_ * OW_]     = acc1[1];
    o1[2 * (size_t)OH_ * OW_] = acc1[2];
    o1[3 * (size_t)OH_ * OW_] = acc1[3];
  }
}

// ------------------------------------------------------------------
extern "C" void kernel_launch(void* const* d_in, const int* in_sizes, int n_in,
                              void* d_out, int out_size, void* d_ws, size_t ws_size,
                              hipStream_t stream) {
  const float* x      = (const float*)d_in[0];
  const float* w_comp = (const float*)d_in[1];
  const float* b_comp = (const float*)d_in[2];
  const float* w_enc  = (const float*)d_in[3];
  const float* b_enc  = (const float*)d_in[4];
  float* out = (float*)d_out;

  u16* bfrB  = (u16*)d_ws;                      // 8,388,608 bf16 (16MB)
  u16* wfrag = bfrB + 8388608;                  //   358,400 bf16
  u16* wcf   = wfrag + 358400;                  //    16,384 bf16
  u16* comp  = wcf + 16384;                     // 1,048,576 bf16
  u16* xw8   = comp + 1048576;                  // 5,898,240 bf16 (~31MB total)

  prep_weights<<<256, 256, 0, stream>>>(w_comp, w_enc, wfrag, wcf, xw8);
  compress_k<<<B_ * H_ * 5, 256, 0, stream>>>(x, wcf, b_comp, comp, xw8);
  enc_mfma_k<<<512, 512, 0, stream>>>(comp, wfrag, b_enc, bfrB);
  carafe_k<<<2048, 256, 0, stream>>>(xw8, bfrB, out);
}